// Round 13
// baseline (229.948 us; speedup 1.0000x reference)
//
#include <hip/hip_runtime.h>
#include <hip/hip_bf16.h>

using bf16 = __hip_bfloat16;
typedef __attribute__((ext_vector_type(8))) short bf16x8;
typedef __attribute__((ext_vector_type(2))) float f32x2;
typedef __attribute__((ext_vector_type(4))) float f32x4;
typedef __attribute__((ext_vector_type(16))) float f32x16;
typedef __attribute__((ext_vector_type(4))) unsigned int u32x4;

#define DEVI __device__ __forceinline__

constexpr int B = 4, C = 128, C2 = 256, H = 96, W = 256;
constexpr int HW = H * W;            // 24576
constexpr int NPIX = B * HW;         // 98304
constexpr int BH = B * H;            // 384
constexpr float SCALE = 0.08838834764831845f; // 128^-0.5
constexpr float LN_EPS = 1e-5f;

DEVI float lo16(unsigned u) { return __builtin_bit_cast(float, u << 16); }
DEVI float hi16(unsigned u) { return __builtin_bit_cast(float, u & 0xffff0000u); }
DEVI unsigned short f2bu(float v) {
    bf16 b = __float2bfloat16(v);
    return __builtin_bit_cast(unsigned short, b);
}
DEVI unsigned packbf2(float a, float b) {
    return (unsigned)f2bu(a) | ((unsigned)f2bu(b) << 16);
}
DEVI f32x2 up2(unsigned p) { return f32x2{lo16(p), hi16(p)}; }

// ---------------------------------------------------------------------------
// W0: convert the 4 weight matrices fp32 -> bf16.
// ---------------------------------------------------------------------------
__global__ __launch_bounds__(256) void wcvt_kernel(
    const float* __restrict__ w0, const float* __restrict__ w1,
    const float* __restrict__ w2, const float* __restrict__ w3,
    unsigned short* __restrict__ o0, unsigned short* __restrict__ o1,
    unsigned short* __restrict__ o2, unsigned short* __restrict__ o3)
{
    const int id = blockIdx.x, t = threadIdx.x;
    const float* src; unsigned short* dst; int base;
    if (id < 8)       { src = w0; dst = o0; base = id * 4096; }
    else if (id < 16) { src = w1; dst = o1; base = (id - 8) * 4096; }
    else if (id < 20) { src = w2; dst = o2; base = (id - 16) * 4096; }
    else              { src = w3; dst = o3; base = (id - 20) * 4096; }
#pragma unroll
    for (int u = 0; u < 4; ++u) {
        int i = base + t * 16 + u * 4;
        float4 v = *reinterpret_cast<const float4*>(&src[i]);
        ushort4 o;
        o.x = f2bu(v.x); o.y = f2bu(v.y); o.z = f2bu(v.z); o.w = f2bu(v.w);
        *reinterpret_cast<ushort4*>(&dst[i]) = o;
    }
}

// ---------------------------------------------------------------------------
// K1: conv1x1 as MFMA GEMM with FUSED NCHW->NHWC transpose, both sides.
// ---------------------------------------------------------------------------
__global__ __launch_bounds__(256) void conv1x1_mfma_kernel(
    const float* __restrict__ x_l, const float* __restrict__ x_r,
    const unsigned short* __restrict__ Wb_l, const unsigned short* __restrict__ Wb_r,
    unsigned short* __restrict__ y_l, unsigned short* __restrict__ y_r)
{
    __shared__ unsigned short xs[64][132];       // [px][c], padded stride 264B
    const int side = blockIdx.x & 1;
    const int u = blockIdx.x >> 1;               // 0..1535 px-blocks
    const float* x = side ? x_r : x_l;
    const unsigned short* Wb = side ? Wb_r : Wb_l;
    unsigned short* y = side ? y_r : y_l;

    const int t = threadIdx.x;
    const int b = u / (HW / 64);
    const int hw0 = (u % (HW / 64)) * 64;

#pragma unroll
    for (int i = 0; i < 8; ++i) {
        const int idx = t + i * 256;
        const int px4 = (idx & 15) * 4;
        const int c = idx >> 4;
        float4 v = *reinterpret_cast<const float4*>(&x[((size_t)b * C + c) * HW + hw0 + px4]);
        xs[px4 + 0][c] = f2bu(v.x);
        xs[px4 + 1][c] = f2bu(v.y);
        xs[px4 + 2][c] = f2bu(v.z);
        xs[px4 + 3][c] = f2bu(v.w);
    }
    __syncthreads();

    const int lane = t & 63, wid = t >> 6;       // wid = oc quarter
    const int l15 = lane & 15, l4 = lane >> 4;

    f32x4 acc[4][4] = {};
    for (int kk = 0; kk < 4; ++kk) {
        const int k0 = kk * 32 + l4 * 8;
        bf16x8 a[4], bb[4];
#pragma unroll
        for (int mt = 0; mt < 4; ++mt)
            a[mt] = *reinterpret_cast<const bf16x8*>(&xs[mt * 16 + l15][k0]);
#pragma unroll
        for (int nt = 0; nt < 4; ++nt)
            bb[nt] = *reinterpret_cast<const bf16x8*>(
                &Wb[(size_t)(wid * 64 + nt * 16 + l15) * C + k0]);
#pragma unroll
        for (int mt = 0; mt < 4; ++mt)
#pragma unroll
            for (int nt = 0; nt < 4; ++nt)
                acc[mt][nt] = __builtin_amdgcn_mfma_f32_16x16x32_bf16(bb[nt], a[mt], acc[mt][nt], 0, 0, 0);
    }
#pragma unroll
    for (int mt = 0; mt < 4; ++mt) {
        const size_t px = (size_t)(b * HW + hw0 + mt * 16 + l15);
#pragma unroll
        for (int nt = 0; nt < 4; ++nt) {
            const int oc = wid * 64 + nt * 16 + l4 * 4;
            uint2 o;
            o.x = packbf2(acc[mt][nt][0], acc[mt][nt][1]);
            o.y = packbf2(acc[mt][nt][2], acc[mt][nt][3]);
            *reinterpret_cast<uint2*>(&y[px * C2 + oc]) = o;
        }
    }
}

// ---------------------------------------------------------------------------
// K2a: depthwise 3x3, V channels only (c<128) -> VT[bh][c][w], direct from
// registers. 128-thr blocks, zero LDS, zero barriers -> pure streaming.
// ---------------------------------------------------------------------------
__global__ __launch_bounds__(128) void dwv_kernel(
    const unsigned short* __restrict__ y_l, const unsigned short* __restrict__ y_r,
    const float* __restrict__ dwk_l, const float* __restrict__ dwk_r,
    unsigned short* __restrict__ VT_l, unsigned short* __restrict__ VT_r)
{
    const int side = blockIdx.x & 1;
    const int u = blockIdx.x >> 1;             // 0..1535
    const unsigned short* y = side ? y_r : y_l;
    const float* dwk = side ? dwk_r : dwk_l;
    unsigned short* VT = side ? VT_r : VT_l;

    const int t = threadIdx.x;
    const int wt = u & 3;
    const int bh = u >> 2;
    const int h = bh % H;
    const int ch8 = t & 15, wi = t >> 4;       // 16 c-octets x 8 w-groups
    const int c0 = ch8 * 8;                    // V channels 0..127
    const int wbase = wt * 64 + wi * 8;

    f32x2 acc2[8][4] = {};
#pragma unroll
    for (int dh = 0; dh < 3; ++dh) {
        const int hh = h + dh - 1;
        if ((unsigned)hh >= (unsigned)H) continue;
        f32x2 wt0[4], wt1[4], wt2[4];
#pragma unroll
        for (int k = 0; k < 4; ++k) {
            const float* d0 = dwk + (c0 + 2 * k) * 9 + dh * 3;
            const float* d1 = dwk + (c0 + 2 * k + 1) * 9 + dh * 3;
            wt0[k] = f32x2{d0[0], d1[0]};
            wt1[k] = f32x2{d0[1], d1[1]};
            wt2[k] = f32x2{d0[2], d1[2]};
        }
        const unsigned short* yrow = y + (size_t)(bh + dh - 1) * W * C2 + c0;
        uint4 uu[10];
#pragma unroll
        for (int j = 0; j < 10; ++j) {
            const int ww = wbase - 1 + j;
            uint4 v = {0u, 0u, 0u, 0u};
            if ((unsigned)ww < 256u)
                v = *reinterpret_cast<const uint4*>(&yrow[(size_t)ww * C2]);
            uu[j] = v;
        }
#pragma unroll
        for (int j = 0; j < 10; ++j) {
            const unsigned arr[4] = {uu[j].x, uu[j].y, uu[j].z, uu[j].w};
            f32x2 v[4];
#pragma unroll
            for (int k = 0; k < 4; ++k) v[k] = up2(arr[k]);
            if (j < 8) {
#pragma unroll
                for (int k = 0; k < 4; ++k) acc2[j][k] += v[k] * wt0[k];
            }
            if (j >= 1 && j <= 8) {
#pragma unroll
                for (int k = 0; k < 4; ++k) acc2[j - 1][k] += v[k] * wt1[k];
            }
            if (j >= 2) {
#pragma unroll
                for (int k = 0; k < 4; ++k) acc2[j - 2][k] += v[k] * wt2[k];
            }
        }
    }
    // direct VT store: channel c0+k, 8 w packed = 16B
#pragma unroll
    for (int k = 0; k < 8; ++k) {
        uint4 o;
        o.x = packbf2(acc2[0][k >> 1][k & 1], acc2[1][k >> 1][k & 1]);
        o.y = packbf2(acc2[2][k >> 1][k & 1], acc2[3][k >> 1][k & 1]);
        o.z = packbf2(acc2[4][k >> 1][k & 1], acc2[5][k >> 1][k & 1]);
        o.w = packbf2(acc2[6][k >> 1][k & 1], acc2[7][k >> 1][k & 1]);
        *reinterpret_cast<uint4*>(&VT[((size_t)bh * C + c0 + k) * W + wbase]) = o;
    }
}

// ---------------------------------------------------------------------------
// K2b: depthwise 3x3 mid channels + LayerNorm + Q-GEMM. 128-thr blocks
// (2 waves), msb LDS only (16KB). Q-GEMM swapped operands -> uint2 stores.
// ---------------------------------------------------------------------------
__global__ __launch_bounds__(128) void dwmid_kernel(
    const unsigned short* __restrict__ y_l, const unsigned short* __restrict__ y_r,
    const float* __restrict__ dwk_l, const float* __restrict__ dwk_r,
    const float* __restrict__ lnw_l, const float* __restrict__ lnb_l,
    const float* __restrict__ lnw_r, const float* __restrict__ lnb_r,
    const unsigned short* __restrict__ Wq_l, const unsigned short* __restrict__ Wq_r,
    const float* __restrict__ bq_l, const float* __restrict__ bq_r,
    unsigned short* __restrict__ q_l, unsigned short* __restrict__ q_r)
{
    __shared__ unsigned char msb[64 * 256];    // [px][c] swizzled bf16
    __shared__ float lnwb[256];

    const int side = blockIdx.x & 1;
    const int u = blockIdx.x >> 1;             // 0..1535
    const unsigned short* y = side ? y_r : y_l;
    const float* dwk = side ? dwk_r : dwk_l;
    const float* lnw = side ? lnw_r : lnw_l;
    const float* lnb = side ? lnb_r : lnb_l;
    const unsigned short* Wqb = side ? Wq_r : Wq_l;
    const float* bq = side ? bq_r : bq_l;
    unsigned short* q = side ? q_r : q_l;

    const int t = threadIdx.x;
    const int wt = u & 3;
    const int bh = u >> 2;
    const int h = bh % H;
    const int ch8 = t & 15, wi = t >> 4;
    const int c0m = ch8 * 8;                   // mid channel offset 0..120
    const int wbase = wt * 64 + wi * 8;

    lnwb[t] = lnw[t];            // t<128: lnw
    lnwb[t + 128] = lnb[t];      // 128..255: lnb

    f32x2 acc2[8][4] = {};
#pragma unroll
    for (int dh = 0; dh < 3; ++dh) {
        const int hh = h + dh - 1;
        if ((unsigned)hh >= (unsigned)H) continue;
        f32x2 wt0[4], wt1[4], wt2[4];
#pragma unroll
        for (int k = 0; k < 4; ++k) {
            const float* d0 = dwk + (128 + c0m + 2 * k) * 9 + dh * 3;
            const float* d1 = dwk + (128 + c0m + 2 * k + 1) * 9 + dh * 3;
            wt0[k] = f32x2{d0[0], d1[0]};
            wt1[k] = f32x2{d0[1], d1[1]};
            wt2[k] = f32x2{d0[2], d1[2]};
        }
        const unsigned short* yrow = y + (size_t)(bh + dh - 1) * W * C2 + 128 + c0m;
        uint4 uu[10];
#pragma unroll
        for (int j = 0; j < 10; ++j) {
            const int ww = wbase - 1 + j;
            uint4 v = {0u, 0u, 0u, 0u};
            if ((unsigned)ww < 256u)
                v = *reinterpret_cast<const uint4*>(&yrow[(size_t)ww * C2]);
            uu[j] = v;
        }
#pragma unroll
        for (int j = 0; j < 10; ++j) {
            const unsigned arr[4] = {uu[j].x, uu[j].y, uu[j].z, uu[j].w};
            f32x2 v[4];
#pragma unroll
            for (int k = 0; k < 4; ++k) v[k] = up2(arr[k]);
            if (j < 8) {
#pragma unroll
                for (int k = 0; k < 4; ++k) acc2[j][k] += v[k] * wt0[k];
            }
            if (j >= 1 && j <= 8) {
#pragma unroll
                for (int k = 0; k < 4; ++k) acc2[j - 1][k] += v[k] * wt1[k];
            }
            if (j >= 2) {
#pragma unroll
                for (int k = 0; k < 4; ++k) acc2[j - 2][k] += v[k] * wt2[k];
            }
        }
    }

    // scatter mid results to msb (swizzled)
#pragma unroll
    for (int i = 0; i < 8; ++i) {
        uint4 o;
        o.x = packbf2(acc2[i][0].x, acc2[i][0].y);
        o.y = packbf2(acc2[i][1].x, acc2[i][1].y);
        o.z = packbf2(acc2[i][2].x, acc2[i][2].y);
        o.w = packbf2(acc2[i][3].x, acc2[i][3].y);
        const int pxl = wi * 8 + i;
        const unsigned addr =
            (unsigned)(pxl * 256 + c0m * 2) ^ (unsigned)((pxl & 7) << 4);
        *reinterpret_cast<uint4*>(msb + addr) = o;
    }
    __syncthreads();

    // ---- LayerNorm: 2 threads per pixel, 64 channels each ----
    {
        const int px = t >> 1, qq = t & 1;
        uint4 raw[8];
#pragma unroll
        for (int v = 0; v < 8; ++v) {
            const unsigned addr =
                (unsigned)(px * 256 + qq * 128 + v * 16) ^ (unsigned)((px & 7) << 4);
            raw[v] = *reinterpret_cast<const uint4*>(msb + addr);
        }
        float s1 = 0.f, s2 = 0.f;
#pragma unroll
        for (int v = 0; v < 8; ++v) {
            const unsigned arr[4] = {raw[v].x, raw[v].y, raw[v].z, raw[v].w};
#pragma unroll
            for (int k = 0; k < 4; ++k) {
                float v0 = lo16(arr[k]), v1 = hi16(arr[k]);
                s1 += v0 + v1; s2 += v0 * v0 + v1 * v1;
            }
        }
        s1 += __shfl_xor(s1, 1); s2 += __shfl_xor(s2, 1);
        const float mu = s1 * (1.f / C);
        const float rs = rsqrtf(s2 * (1.f / C) - mu * mu + LN_EPS);
#pragma unroll
        for (int v = 0; v < 8; ++v) {
            const unsigned arr[4] = {raw[v].x, raw[v].y, raw[v].z, raw[v].w};
            float nv[8];
#pragma unroll
            for (int k = 0; k < 4; ++k) {
                int c = qq * 64 + v * 8 + k * 2;
                nv[k * 2]     = (lo16(arr[k]) - mu) * rs * lnwb[c] + lnwb[128 + c];
                nv[k * 2 + 1] = (hi16(arr[k]) - mu) * rs * lnwb[c + 1] + lnwb[128 + c + 1];
            }
            uint4 wv;
            wv.x = packbf2(nv[0], nv[1]); wv.y = packbf2(nv[2], nv[3]);
            wv.z = packbf2(nv[4], nv[5]); wv.w = packbf2(nv[6], nv[7]);
            const unsigned addr =
                (unsigned)(px * 256 + qq * 128 + v * 16) ^ (unsigned)((px & 7) << 4);
            *reinterpret_cast<uint4*>(msb + addr) = wv;
        }
    }
    __syncthreads();

    // ---- Q-GEMM: 2 waves x 2 px-tiles x 8 oc-tiles; swapped operands ----
    {
        const int lane = t & 63, wid = t >> 6;
        const int l15 = lane & 15, l4 = lane >> 4;
        f32x4 acc[2][8] = {};
        for (int kk = 0; kk < 4; ++kk) {
            const int k0 = kk * 32 + l4 * 8;
            bf16x8 a[2];
#pragma unroll
            for (int pt = 0; pt < 2; ++pt) {
                const int pxl = (wid * 2 + pt) * 16 + l15;
                const unsigned aaddr =
                    (unsigned)(pxl * 256 + k0 * 2) ^ (unsigned)((pxl & 7) << 4);
                a[pt] = *reinterpret_cast<const bf16x8*>(msb + aaddr);
            }
#pragma unroll
            for (int nt = 0; nt < 8; ++nt) {
                bf16x8 bv = *reinterpret_cast<const bf16x8*>(
                    &Wqb[(size_t)(nt * 16 + l15) * C + k0]);
#pragma unroll
                for (int pt = 0; pt < 2; ++pt)
                    acc[pt][nt] = __builtin_amdgcn_mfma_f32_16x16x32_bf16(bv, a[pt], acc[pt][nt], 0, 0, 0);
            }
        }
        // D[oc][px]: lane l15 = px, regs = 4 consecutive oc -> uint2 stores
        const size_t px0 = (size_t)bh * W + wt * 64;
#pragma unroll
        for (int pt = 0; pt < 2; ++pt) {
            const size_t px = px0 + (wid * 2 + pt) * 16 + l15;
#pragma unroll
            for (int nt = 0; nt < 8; ++nt) {
                const int oc = nt * 16 + l4 * 4;
                const float4 bias = *reinterpret_cast<const float4*>(&bq[oc]);
                uint2 o;
                o.x = packbf2(acc[pt][nt][0] + bias.x, acc[pt][nt][1] + bias.y);
                o.y = packbf2(acc[pt][nt][2] + bias.z, acc[pt][nt][3] + bias.w);
                *reinterpret_cast<uint2*>(&q[px * C + oc]) = o;
            }
        }
    }
}

// ---------------------------------------------------------------------------
// FUSED attention v5: swapped-operand QK^T (S^T = K·Q^T, 32x32x16 MFMA),
// in-register softmax + P->B-frag conversion, K & VT staged in LDS.
// ---------------------------------------------------------------------------
__global__ __launch_bounds__(256, 2) void fused_attn_kernel(
    const unsigned short* __restrict__ Q_l, const unsigned short* __restrict__ Q_r,
    const unsigned short* __restrict__ VT_l, const unsigned short* __restrict__ VT_r,
    const float* __restrict__ x_l, const float* __restrict__ x_r,
    const float* __restrict__ beta, const float* __restrict__ gamma,
    float* __restrict__ out_l, float* __restrict__ out_r)
{
    __shared__ __align__(16) unsigned char lds[65536];  // K chunk 32KB | VT chunk 32KB
    const int bid = blockIdx.x;
    const int xcd = bid & 7;
    const int local = bid >> 3;          // 0..191
    const int bh = xcd * 48 + (local >> 2);
    const int sub = local & 3;
    const int side = sub & 1, half = sub >> 1;

    const unsigned short* Q  = side ? Q_r : Q_l;
    const unsigned short* K  = side ? Q_l : Q_r;
    const unsigned short* VT = side ? VT_l : VT_r;
    const float* x    = side ? x_r : x_l;
    const float* coef = side ? gamma : beta;
    float* out        = side ? out_r : out_l;

    const int t = threadIdx.x;
    const int lane = t & 63, wv = t >> 6;
    const int l31 = lane & 31, hi = lane >> 5;
    const int b = bh / H, h = bh % H;
    const int w0 = half * 128 + wv * 32;     // this wave's 32 q-rows

    // ---- Q B-frags: col = own q-row (l31), k-slice hi*8, 8 k-steps ----
    const unsigned short* qrow = Q + ((size_t)bh * W + w0 + l31) * C + hi * 8;
    bf16x8 qfrag[8];
#pragma unroll
    for (int ks = 0; ks < 8; ++ks)
        qfrag[ks] = *reinterpret_cast<const bf16x8*>(qrow + ks * 16);

    const char* kg = (const char*)(K + (size_t)bh * W * C);
    const char* vg = (const char*)(VT + (size_t)bh * C * W);
    const int srow = lane >> 4;
    const int scol = (lane & 15) * 16;

    float sden_loc = 0.f;
    f32x16 oacc[4] = {};

    for (int ci = 0; ci < 2; ++ci) {
        // ---- stage K chunk [128v][128c] + VT chunk [128c][128v] ----
#pragma unroll
        for (int i = 0; i < 8; ++i) {
            const int r0 = wv * 32 + i * 4;
            const int row = r0 + srow;
            const char* src = kg + (size_t)(ci * 128 + row) * 256 + (scol ^ ((row & 7) << 4));
            __builtin_amdgcn_global_load_lds(
                (const __attribute__((address_space(1))) void*)src,
                (__attribute__((address_space(3))) void*)(lds + r0 * 256), 16, 0, 0);
        }
#pragma unroll
        for (int i = 0; i < 8; ++i) {
            const int r0 = wv * 32 + i * 4;
            const int row = r0 + srow;
            const char* src = vg + (size_t)row * 512 + ci * 256 + (scol ^ ((row & 7) << 4));
            __builtin_amdgcn_global_load_lds(
                (const __attribute__((address_space(1))) void*)src,
                (__attribute__((address_space(3))) void*)(lds + 32768 + r0 * 256), 16, 0, 0);
        }
        __syncthreads();

        // ---- S^T chunk = K_chunk · Q^T : 4 v-tiles of 32 ----
        f32x16 sacc[4] = {};
        __builtin_amdgcn_s_setprio(1);
#pragma unroll
        for (int vt = 0; vt < 4; ++vt) {
            const int row = vt * 32 + l31;
            const unsigned rb = row * 256;
            const unsigned sw = (row & 7) << 4;
#pragma unroll
            for (int ks = 0; ks < 8; ++ks) {
                bf16x8 a = *reinterpret_cast<const bf16x8*>(
                    lds + rb + ((ks * 32 + hi * 16) ^ sw));
                sacc[vt] = __builtin_amdgcn_mfma_f32_32x32x16_bf16(a, qfrag[ks], sacc[vt], 0, 0, 0);
            }
        }
        __builtin_amdgcn_s_setprio(0);

        // ---- max-free softmax numerators + partial denominator ----
#pragma unroll
        for (int vt = 0; vt < 4; ++vt)
#pragma unroll
            for (int r = 0; r < 16; ++r) {
                float e = __expf(sacc[vt][r] * SCALE);
                sacc[vt][r] = e;
                sden_loc += e;
            }

        // ---- P -> bf16 B-frags, in-register (pack + half-swap) ----
        unsigned pw[8][4];
#pragma unroll
        for (int g = 0; g < 8; ++g) {
            const int vt = g >> 1, bs = (g & 1) * 8;
            unsigned pa = packbf2(sacc[vt][bs + 0], sacc[vt][bs + 1]);
            unsigned pc = packbf2(sacc[vt][bs + 2], sacc[vt][bs + 3]);
            unsigned pb = packbf2(sacc[vt][bs + 4], sacc[vt][bs + 5]);
            unsigned pd = packbf2(sacc[vt][bs + 6], sacc[vt][bs + 7]);
            unsigned sa = __shfl_xor(pa, 32);
            unsigned sb = __shfl_xor(pb, 32);
            unsigned sc = __shfl_xor(pc, 32);
            unsigned sd = __shfl_xor(pd, 32);
            pw[g][0] = hi ? sb : pa;
            pw[g][1] = hi ? sd : pc;
            pw[g][2] = hi ? pb : sa;
            pw[g][3] = hi ? pd : sc;
        }

        // ---- O^T += VT_chunk · P^T : 4 c-tiles, 8 v-groups ----
        __builtin_amdgcn_s_setprio(1);
#pragma unroll
        for (int ct = 0; ct < 4; ++ct) {
            const int row = ct * 32 + l31;
            const unsigned rb = 32768 + row * 256;
            const unsigned sw = (row & 7) << 4;
#pragma unroll
            for (int g = 0; g < 8; ++g) {
                bf16x8 va = *reinterpret_cast<const bf16x8*>(
                    lds + rb + ((g * 32 + hi * 16) ^ sw));
                u32x4 pv = {pw[g][0], pw[g][1], pw[g][2], pw[g][3]};
                oacc[ct] = __builtin_amdgcn_mfma_f32_32x32x16_bf16(
                    va, __builtin_bit_cast(bf16x8, pv), oacc[ct], 0, 0, 0);
            }
        }
        __builtin_amdgcn_s_setprio(0);
        __syncthreads();   // all waves done with this chunk's K/VT
    }

    // ---- epilogue: lane holds O^T[c = ct*32+crow][w = w0+l31] ----
    const float sden = sden_loc + __shfl_xor(sden_loc, 32);
    const float inv = 1.f / sden;
    const size_t base0 = (size_t)b * C * HW + (size_t)h * W + w0 + l31;
#pragma unroll
    for (int ct = 0; ct < 4; ++ct)
#pragma unroll
        for (int r = 0; r < 16; ++r) {
            const int c = ct * 32 + (r & 3) + 8 * (r >> 2) + 4 * hi;
            const size_t a = base0 + (size_t)c * HW;
            out[a] = x[a] + oacc[ct][r] * inv * coef[c];
        }
}

// ---------------------------------------------------------------------------
extern "C" void kernel_launch(void* const* d_in, const int* in_sizes, int n_in,
                              void* d_out, int out_size, void* d_ws, size_t ws_size,
                              hipStream_t stream) {
    (void)in_sizes; (void)n_in; (void)out_size; (void)ws_size;
    const float* x_l   = (const float*)d_in[0];
    const float* x_r   = (const float*)d_in[1];
    const float* Wl_m  = (const float*)d_in[2];
    const float* Wr_m  = (const float*)d_in[3];
    const float* dw_l  = (const float*)d_in[4];
    const float* dw_r  = (const float*)d_in[5];
    const float* lnl_w = (const float*)d_in[6];
    const float* lnl_b = (const float*)d_in[7];
    const float* lnr_w = (const float*)d_in[8];
    const float* lnr_b = (const float*)d_in[9];
    const float* Wq_l  = (const float*)d_in[10];
    const float* bq_l  = (const float*)d_in[11];
    const float* Wq_r  = (const float*)d_in[12];
    const float* bq_r  = (const float*)d_in[13];
    const float* beta  = (const float*)d_in[14];
    const float* gamma = (const float*)d_in[15];

    char* ws = (char*)d_ws;
    unsigned short* ymid_l   = (unsigned short*)(ws + 0);            // 50,331,648
    unsigned short* ymid_r   = (unsigned short*)(ws + 50331648);     // 50,331,648
    unsigned short* VT_l     = (unsigned short*)(ws + 150994944);    // 25,165,824
    unsigned short* VT_r     = (unsigned short*)(ws + 176160768);    // 25,165,824
    unsigned short* Q_l      = (unsigned short*)(ws + 201326592);    // 25,165,824
    unsigned short* Q_r      = (unsigned short*)(ws + 226492416);    // 25,165,824
    unsigned short* Wlb      = (unsigned short*)(ws + 251658240);    // 65,536
    unsigned short* Wrb      = (unsigned short*)(ws + 251723776);    // 65,536
    unsigned short* Wqlb     = (unsigned short*)(ws + 251789312);    // 32,768
    unsigned short* Wqrb     = (unsigned short*)(ws + 251822080);    // 32,768

    float* out_l = (float*)d_out;
    float* out_r = out_l + (size_t)B * C * HW;

    const dim3 blk(256);

    wcvt_kernel<<<24, blk, 0, stream>>>(Wl_m, Wr_m, Wq_l, Wq_r, Wlb, Wrb, Wqlb, Wqrb);

    conv1x1_mfma_kernel<<<3072, blk, 0, stream>>>(x_l, x_r, Wlb, Wrb, ymid_l, ymid_r);
    dwv_kernel<<<3072, dim3(128), 0, stream>>>(ymid_l, ymid_r, dw_l, dw_r, VT_l, VT_r);
    dwmid_kernel<<<3072, dim3(128), 0, stream>>>(ymid_l, ymid_r, dw_l, dw_r,
                                                 lnl_w, lnl_b, lnr_w, lnr_b,
                                                 Wqlb, Wqrb, bq_l, bq_r, Q_l, Q_r);
    fused_attn_kernel<<<1536, blk, 0, stream>>>(Q_l, Q_r, VT_l, VT_r,
                                                x_l, x_r, beta, gamma, out_l, out_r);
}

// Round 14
// 228.198 us; speedup vs baseline: 1.0077x; 1.0077x over previous
//
#include <hip/hip_runtime.h>
#include <hip/hip_bf16.h>

using bf16 = __hip_bfloat16;
typedef __attribute__((ext_vector_type(8))) short bf16x8;
typedef __attribute__((ext_vector_type(2))) float f32x2;
typedef __attribute__((ext_vector_type(4))) float f32x4;
typedef __attribute__((ext_vector_type(16))) float f32x16;
typedef __attribute__((ext_vector_type(4))) unsigned int u32x4;

#define DEVI __device__ __forceinline__

constexpr int B = 4, C = 128, C2 = 256, H = 96, W = 256;
constexpr int HW = H * W;            // 24576
constexpr int NPIX = B * HW;         // 98304
constexpr int BH = B * H;            // 384
constexpr float SCALE = 0.08838834764831845f; // 128^-0.5
constexpr float LN_EPS = 1e-5f;

DEVI float lo16(unsigned u) { return __builtin_bit_cast(float, u << 16); }
DEVI float hi16(unsigned u) { return __builtin_bit_cast(float, u & 0xffff0000u); }
DEVI unsigned short f2bu(float v) {
    bf16 b = __float2bfloat16(v);
    return __builtin_bit_cast(unsigned short, b);
}
DEVI unsigned packbf2(float a, float b) {
    return (unsigned)f2bu(a) | ((unsigned)f2bu(b) << 16);
}
DEVI f32x2 up2(unsigned p) { return f32x2{lo16(p), hi16(p)}; }

// ---------------------------------------------------------------------------
// W0: convert the 4 weight matrices fp32 -> bf16.
// ---------------------------------------------------------------------------
__global__ __launch_bounds__(256) void wcvt_kernel(
    const float* __restrict__ w0, const float* __restrict__ w1,
    const float* __restrict__ w2, const float* __restrict__ w3,
    unsigned short* __restrict__ o0, unsigned short* __restrict__ o1,
    unsigned short* __restrict__ o2, unsigned short* __restrict__ o3)
{
    const int id = blockIdx.x, t = threadIdx.x;
    const float* src; unsigned short* dst; int base;
    if (id < 8)       { src = w0; dst = o0; base = id * 4096; }
    else if (id < 16) { src = w1; dst = o1; base = (id - 8) * 4096; }
    else if (id < 20) { src = w2; dst = o2; base = (id - 16) * 4096; }
    else              { src = w3; dst = o3; base = (id - 20) * 4096; }
#pragma unroll
    for (int u = 0; u < 4; ++u) {
        int i = base + t * 16 + u * 4;
        float4 v = *reinterpret_cast<const float4*>(&src[i]);
        ushort4 o;
        o.x = f2bu(v.x); o.y = f2bu(v.y); o.z = f2bu(v.z); o.w = f2bu(v.w);
        *reinterpret_cast<ushort4*>(&dst[i]) = o;
    }
}

// ---------------------------------------------------------------------------
// K1: conv1x1 as MFMA GEMM with FUSED NCHW->NHWC transpose, both sides.
// Round-14: (a) XOR-swizzled xs (msb pattern) with 16B uint4 staging writes
// (8ch x 1px assembled in registers) -> kills the ~8-way write conflicts of
// the padded-132 scalar-ushort path; (b) all 16 W B-frags hoisted to
// registers before staging -> k-loop is pure LDS-read + MFMA.
// ---------------------------------------------------------------------------
__global__ __launch_bounds__(256) void conv1x1_mfma_kernel(
    const float* __restrict__ x_l, const float* __restrict__ x_r,
    const unsigned short* __restrict__ Wb_l, const unsigned short* __restrict__ Wb_r,
    unsigned short* __restrict__ y_l, unsigned short* __restrict__ y_r)
{
    __shared__ unsigned char xs[64 * 256];       // [px][c] bf16, XOR-swizzled
    const int side = blockIdx.x & 1;
    const int u = blockIdx.x >> 1;               // 0..1535 px-blocks
    const float* x = side ? x_r : x_l;
    const unsigned short* Wb = side ? Wb_r : Wb_l;
    unsigned short* y = side ? y_r : y_l;

    const int t = threadIdx.x;
    const int b = u / (HW / 64);
    const int hw0 = (u % (HW / 64)) * 64;

    const int lane = t & 63, wid = t >> 6;       // wid = oc quarter
    const int l15 = lane & 15, l4 = lane >> 4;

    // ---- hoist all W B-frags for this wave's oc quarter (64 VGPR) ----
    bf16x8 wfrag[4][4];                          // [kk][nt]
#pragma unroll
    for (int kk = 0; kk < 4; ++kk)
#pragma unroll
        for (int nt = 0; nt < 4; ++nt)
            wfrag[kk][nt] = *reinterpret_cast<const bf16x8*>(
                &Wb[(size_t)(wid * 64 + nt * 16 + l15) * C + kk * 32 + l4 * 8]);

    // ---- stage: 8ch x 4px per thread; register micro-transpose; uint4 writes ----
    {
        const int px4 = (t & 15) * 4;
        const int c8 = (t >> 4) * 8;
        float v_[8][4];
#pragma unroll
        for (int j = 0; j < 8; ++j) {
            float4 v = *reinterpret_cast<const float4*>(
                &x[((size_t)b * C + c8 + j) * HW + hw0 + px4]);
            v_[j][0] = v.x; v_[j][1] = v.y; v_[j][2] = v.z; v_[j][3] = v.w;
        }
#pragma unroll
        for (int i = 0; i < 4; ++i) {
            const int px = px4 + i;
            uint4 o;
            o.x = packbf2(v_[0][i], v_[1][i]);
            o.y = packbf2(v_[2][i], v_[3][i]);
            o.z = packbf2(v_[4][i], v_[5][i]);
            o.w = packbf2(v_[6][i], v_[7][i]);
            const unsigned addr =
                (unsigned)(px * 256) + (((unsigned)(c8 * 2)) ^ (unsigned)((px & 7) << 4));
            *reinterpret_cast<uint4*>(xs + addr) = o;
        }
    }
    __syncthreads();

    f32x4 acc[4][4] = {};                        // [mt px-tile][nt oc-tile]
#pragma unroll
    for (int kk = 0; kk < 4; ++kk) {
        const int k0b = (kk * 32 + l4 * 8) * 2;  // byte offset within row
        bf16x8 a[4];
#pragma unroll
        for (int mt = 0; mt < 4; ++mt) {
            const int pxl = mt * 16 + l15;
            const unsigned aaddr =
                (unsigned)(pxl * 256) + (((unsigned)k0b) ^ (unsigned)((pxl & 7) << 4));
            a[mt] = *reinterpret_cast<const bf16x8*>(xs + aaddr);
        }
#pragma unroll
        for (int mt = 0; mt < 4; ++mt)
#pragma unroll
            for (int nt = 0; nt < 4; ++nt)
                acc[mt][nt] = __builtin_amdgcn_mfma_f32_16x16x32_bf16(
                    wfrag[kk][nt], a[mt], acc[mt][nt], 0, 0, 0);
    }
    // D[oc][px]: lane l15 = px, regs = 4 consecutive oc -> uint2 stores
#pragma unroll
    for (int mt = 0; mt < 4; ++mt) {
        const size_t px = (size_t)(b * HW + hw0 + mt * 16 + l15);
#pragma unroll
        for (int nt = 0; nt < 4; ++nt) {
            const int oc = wid * 64 + nt * 16 + l4 * 4;
            uint2 o;
            o.x = packbf2(acc[mt][nt][0], acc[mt][nt][1]);
            o.y = packbf2(acc[mt][nt][2], acc[mt][nt][3]);
            *reinterpret_cast<uint2*>(&y[px * C2 + oc]) = o;
        }
    }
}

// ---------------------------------------------------------------------------
// K2a: depthwise 3x3, V channels only (c<128) -> VT[bh][c][w], direct from
// registers. 128-thr blocks, zero LDS, zero barriers -> pure streaming.
// ---------------------------------------------------------------------------
__global__ __launch_bounds__(128) void dwv_kernel(
    const unsigned short* __restrict__ y_l, const unsigned short* __restrict__ y_r,
    const float* __restrict__ dwk_l, const float* __restrict__ dwk_r,
    unsigned short* __restrict__ VT_l, unsigned short* __restrict__ VT_r)
{
    const int side = blockIdx.x & 1;
    const int u = blockIdx.x >> 1;             // 0..1535
    const unsigned short* y = side ? y_r : y_l;
    const float* dwk = side ? dwk_r : dwk_l;
    unsigned short* VT = side ? VT_r : VT_l;

    const int t = threadIdx.x;
    const int wt = u & 3;
    const int bh = u >> 2;
    const int h = bh % H;
    const int ch8 = t & 15, wi = t >> 4;       // 16 c-octets x 8 w-groups
    const int c0 = ch8 * 8;
    const int wbase = wt * 64 + wi * 8;

    f32x2 acc2[8][4] = {};
#pragma unroll
    for (int dh = 0; dh < 3; ++dh) {
        const int hh = h + dh - 1;
        if ((unsigned)hh >= (unsigned)H) continue;
        f32x2 wt0[4], wt1[4], wt2[4];
#pragma unroll
        for (int k = 0; k < 4; ++k) {
            const float* d0 = dwk + (c0 + 2 * k) * 9 + dh * 3;
            const float* d1 = dwk + (c0 + 2 * k + 1) * 9 + dh * 3;
            wt0[k] = f32x2{d0[0], d1[0]};
            wt1[k] = f32x2{d0[1], d1[1]};
            wt2[k] = f32x2{d0[2], d1[2]};
        }
        const unsigned short* yrow = y + (size_t)(bh + dh - 1) * W * C2 + c0;
        uint4 uu[10];
#pragma unroll
        for (int j = 0; j < 10; ++j) {
            const int ww = wbase - 1 + j;
            uint4 v = {0u, 0u, 0u, 0u};
            if ((unsigned)ww < 256u)
                v = *reinterpret_cast<const uint4*>(&yrow[(size_t)ww * C2]);
            uu[j] = v;
        }
#pragma unroll
        for (int j = 0; j < 10; ++j) {
            const unsigned arr[4] = {uu[j].x, uu[j].y, uu[j].z, uu[j].w};
            f32x2 v[4];
#pragma unroll
            for (int k = 0; k < 4; ++k) v[k] = up2(arr[k]);
            if (j < 8) {
#pragma unroll
                for (int k = 0; k < 4; ++k) acc2[j][k] += v[k] * wt0[k];
            }
            if (j >= 1 && j <= 8) {
#pragma unroll
                for (int k = 0; k < 4; ++k) acc2[j - 1][k] += v[k] * wt1[k];
            }
            if (j >= 2) {
#pragma unroll
                for (int k = 0; k < 4; ++k) acc2[j - 2][k] += v[k] * wt2[k];
            }
        }
    }
#pragma unroll
    for (int k = 0; k < 8; ++k) {
        uint4 o;
        o.x = packbf2(acc2[0][k >> 1][k & 1], acc2[1][k >> 1][k & 1]);
        o.y = packbf2(acc2[2][k >> 1][k & 1], acc2[3][k >> 1][k & 1]);
        o.z = packbf2(acc2[4][k >> 1][k & 1], acc2[5][k >> 1][k & 1]);
        o.w = packbf2(acc2[6][k >> 1][k & 1], acc2[7][k >> 1][k & 1]);
        *reinterpret_cast<uint4*>(&VT[((size_t)bh * C + c0 + k) * W + wbase]) = o;
    }
}

// ---------------------------------------------------------------------------
// K2b: depthwise 3x3 mid channels + LayerNorm + Q-GEMM. 128-thr blocks
// (2 waves), msb LDS only (16KB). Q-GEMM swapped operands -> uint2 stores.
// ---------------------------------------------------------------------------
__global__ __launch_bounds__(128) void dwmid_kernel(
    const unsigned short* __restrict__ y_l, const unsigned short* __restrict__ y_r,
    const float* __restrict__ dwk_l, const float* __restrict__ dwk_r,
    const float* __restrict__ lnw_l, const float* __restrict__ lnb_l,
    const float* __restrict__ lnw_r, const float* __restrict__ lnb_r,
    const unsigned short* __restrict__ Wq_l, const unsigned short* __restrict__ Wq_r,
    const float* __restrict__ bq_l, const float* __restrict__ bq_r,
    unsigned short* __restrict__ q_l, unsigned short* __restrict__ q_r)
{
    __shared__ unsigned char msb[64 * 256];    // [px][c] swizzled bf16
    __shared__ float lnwb[256];

    const int side = blockIdx.x & 1;
    const int u = blockIdx.x >> 1;             // 0..1535
    const unsigned short* y = side ? y_r : y_l;
    const float* dwk = side ? dwk_r : dwk_l;
    const float* lnw = side ? lnw_r : lnw_l;
    const float* lnb = side ? lnb_r : lnb_l;
    const unsigned short* Wqb = side ? Wq_r : Wq_l;
    const float* bq = side ? bq_r : bq_l;
    unsigned short* q = side ? q_r : q_l;

    const int t = threadIdx.x;
    const int wt = u & 3;
    const int bh = u >> 2;
    const int h = bh % H;
    const int ch8 = t & 15, wi = t >> 4;
    const int c0m = ch8 * 8;
    const int wbase = wt * 64 + wi * 8;

    lnwb[t] = lnw[t];
    lnwb[t + 128] = lnb[t];

    f32x2 acc2[8][4] = {};
#pragma unroll
    for (int dh = 0; dh < 3; ++dh) {
        const int hh = h + dh - 1;
        if ((unsigned)hh >= (unsigned)H) continue;
        f32x2 wt0[4], wt1[4], wt2[4];
#pragma unroll
        for (int k = 0; k < 4; ++k) {
            const float* d0 = dwk + (128 + c0m + 2 * k) * 9 + dh * 3;
            const float* d1 = dwk + (128 + c0m + 2 * k + 1) * 9 + dh * 3;
            wt0[k] = f32x2{d0[0], d1[0]};
            wt1[k] = f32x2{d0[1], d1[1]};
            wt2[k] = f32x2{d0[2], d1[2]};
        }
        const unsigned short* yrow = y + (size_t)(bh + dh - 1) * W * C2 + 128 + c0m;
        uint4 uu[10];
#pragma unroll
        for (int j = 0; j < 10; ++j) {
            const int ww = wbase - 1 + j;
            uint4 v = {0u, 0u, 0u, 0u};
            if ((unsigned)ww < 256u)
                v = *reinterpret_cast<const uint4*>(&yrow[(size_t)ww * C2]);
            uu[j] = v;
        }
#pragma unroll
        for (int j = 0; j < 10; ++j) {
            const unsigned arr[4] = {uu[j].x, uu[j].y, uu[j].z, uu[j].w};
            f32x2 v[4];
#pragma unroll
            for (int k = 0; k < 4; ++k) v[k] = up2(arr[k]);
            if (j < 8) {
#pragma unroll
                for (int k = 0; k < 4; ++k) acc2[j][k] += v[k] * wt0[k];
            }
            if (j >= 1 && j <= 8) {
#pragma unroll
                for (int k = 0; k < 4; ++k) acc2[j - 1][k] += v[k] * wt1[k];
            }
            if (j >= 2) {
#pragma unroll
                for (int k = 0; k < 4; ++k) acc2[j - 2][k] += v[k] * wt2[k];
            }
        }
    }

#pragma unroll
    for (int i = 0; i < 8; ++i) {
        uint4 o;
        o.x = packbf2(acc2[i][0].x, acc2[i][0].y);
        o.y = packbf2(acc2[i][1].x, acc2[i][1].y);
        o.z = packbf2(acc2[i][2].x, acc2[i][2].y);
        o.w = packbf2(acc2[i][3].x, acc2[i][3].y);
        const int pxl = wi * 8 + i;
        const unsigned addr =
            (unsigned)(pxl * 256 + c0m * 2) ^ (unsigned)((pxl & 7) << 4);
        *reinterpret_cast<uint4*>(msb + addr) = o;
    }
    __syncthreads();

    {
        const int px = t >> 1, qq = t & 1;
        uint4 raw[8];
#pragma unroll
        for (int v = 0; v < 8; ++v) {
            const unsigned addr =
                (unsigned)(px * 256 + qq * 128 + v * 16) ^ (unsigned)((px & 7) << 4);
            raw[v] = *reinterpret_cast<const uint4*>(msb + addr);
        }
        float s1 = 0.f, s2 = 0.f;
#pragma unroll
        for (int v = 0; v < 8; ++v) {
            const unsigned arr[4] = {raw[v].x, raw[v].y, raw[v].z, raw[v].w};
#pragma unroll
            for (int k = 0; k < 4; ++k) {
                float v0 = lo16(arr[k]), v1 = hi16(arr[k]);
                s1 += v0 + v1; s2 += v0 * v0 + v1 * v1;
            }
        }
        s1 += __shfl_xor(s1, 1); s2 += __shfl_xor(s2, 1);
        const float mu = s1 * (1.f / C);
        const float rs = rsqrtf(s2 * (1.f / C) - mu * mu + LN_EPS);
#pragma unroll
        for (int v = 0; v < 8; ++v) {
            const unsigned arr[4] = {raw[v].x, raw[v].y, raw[v].z, raw[v].w};
            float nv[8];
#pragma unroll
            for (int k = 0; k < 4; ++k) {
                int c = qq * 64 + v * 8 + k * 2;
                nv[k * 2]     = (lo16(arr[k]) - mu) * rs * lnwb[c] + lnwb[128 + c];
                nv[k * 2 + 1] = (hi16(arr[k]) - mu) * rs * lnwb[c + 1] + lnwb[128 + c + 1];
            }
            uint4 wv;
            wv.x = packbf2(nv[0], nv[1]); wv.y = packbf2(nv[2], nv[3]);
            wv.z = packbf2(nv[4], nv[5]); wv.w = packbf2(nv[6], nv[7]);
            const unsigned addr =
                (unsigned)(px * 256 + qq * 128 + v * 16) ^ (unsigned)((px & 7) << 4);
            *reinterpret_cast<uint4*>(msb + addr) = wv;
        }
    }
    __syncthreads();

    {
        const int lane = t & 63, wid = t >> 6;
        const int l15 = lane & 15, l4 = lane >> 4;
        f32x4 acc[2][8] = {};
        for (int kk = 0; kk < 4; ++kk) {
            const int k0 = kk * 32 + l4 * 8;
            bf16x8 a[2];
#pragma unroll
            for (int pt = 0; pt < 2; ++pt) {
                const int pxl = (wid * 2 + pt) * 16 + l15;
                const unsigned aaddr =
                    (unsigned)(pxl * 256 + k0 * 2) ^ (unsigned)((pxl & 7) << 4);
                a[pt] = *reinterpret_cast<const bf16x8*>(msb + aaddr);
            }
#pragma unroll
            for (int nt = 0; nt < 8; ++nt) {
                bf16x8 bv = *reinterpret_cast<const bf16x8*>(
                    &Wqb[(size_t)(nt * 16 + l15) * C + k0]);
#pragma unroll
                for (int pt = 0; pt < 2; ++pt)
                    acc[pt][nt] = __builtin_amdgcn_mfma_f32_16x16x32_bf16(bv, a[pt], acc[pt][nt], 0, 0, 0);
            }
        }
        const size_t px0 = (size_t)bh * W + wt * 64;
#pragma unroll
        for (int pt = 0; pt < 2; ++pt) {
            const size_t px = px0 + (wid * 2 + pt) * 16 + l15;
#pragma unroll
            for (int nt = 0; nt < 8; ++nt) {
                const int oc = nt * 16 + l4 * 4;
                const float4 bias = *reinterpret_cast<const float4*>(&bq[oc]);
                uint2 o;
                o.x = packbf2(acc[pt][nt][0] + bias.x, acc[pt][nt][1] + bias.y);
                o.y = packbf2(acc[pt][nt][2] + bias.z, acc[pt][nt][3] + bias.w);
                *reinterpret_cast<uint2*>(&q[px * C + oc]) = o;
            }
        }
    }
}

// ---------------------------------------------------------------------------
// FUSED attention v5: swapped-operand QK^T (S^T = K·Q^T, 32x32x16 MFMA),
// in-register softmax + P->B-frag conversion, K & VT staged in LDS.
// ---------------------------------------------------------------------------
__global__ __launch_bounds__(256, 2) void fused_attn_kernel(
    const unsigned short* __restrict__ Q_l, const unsigned short* __restrict__ Q_r,
    const unsigned short* __restrict__ VT_l, const unsigned short* __restrict__ VT_r,
    const float* __restrict__ x_l, const float* __restrict__ x_r,
    const float* __restrict__ beta, const float* __restrict__ gamma,
    float* __restrict__ out_l, float* __restrict__ out_r)
{
    __shared__ __align__(16) unsigned char lds[65536];  // K chunk 32KB | VT chunk 32KB
    const int bid = blockIdx.x;
    const int xcd = bid & 7;
    const int local = bid >> 3;          // 0..191
    const int bh = xcd * 48 + (local >> 2);
    const int sub = local & 3;
    const int side = sub & 1, half = sub >> 1;

    const unsigned short* Q  = side ? Q_r : Q_l;
    const unsigned short* K  = side ? Q_l : Q_r;
    const unsigned short* VT = side ? VT_l : VT_r;
    const float* x    = side ? x_r : x_l;
    const float* coef = side ? gamma : beta;
    float* out        = side ? out_r : out_l;

    const int t = threadIdx.x;
    const int lane = t & 63, wv = t >> 6;
    const int l31 = lane & 31, hi = lane >> 5;
    const int b = bh / H, h = bh % H;
    const int w0 = half * 128 + wv * 32;     // this wave's 32 q-rows

    const unsigned short* qrow = Q + ((size_t)bh * W + w0 + l31) * C + hi * 8;
    bf16x8 qfrag[8];
#pragma unroll
    for (int ks = 0; ks < 8; ++ks)
        qfrag[ks] = *reinterpret_cast<const bf16x8*>(qrow + ks * 16);

    const char* kg = (const char*)(K + (size_t)bh * W * C);
    const char* vg = (const char*)(VT + (size_t)bh * C * W);
    const int srow = lane >> 4;
    const int scol = (lane & 15) * 16;

    float sden_loc = 0.f;
    f32x16 oacc[4] = {};

    for (int ci = 0; ci < 2; ++ci) {
#pragma unroll
        for (int i = 0; i < 8; ++i) {
            const int r0 = wv * 32 + i * 4;
            const int row = r0 + srow;
            const char* src = kg + (size_t)(ci * 128 + row) * 256 + (scol ^ ((row & 7) << 4));
            __builtin_amdgcn_global_load_lds(
                (const __attribute__((address_space(1))) void*)src,
                (__attribute__((address_space(3))) void*)(lds + r0 * 256), 16, 0, 0);
        }
#pragma unroll
        for (int i = 0; i < 8; ++i) {
            const int r0 = wv * 32 + i * 4;
            const int row = r0 + srow;
            const char* src = vg + (size_t)row * 512 + ci * 256 + (scol ^ ((row & 7) << 4));
            __builtin_amdgcn_global_load_lds(
                (const __attribute__((address_space(1))) void*)src,
                (__attribute__((address_space(3))) void*)(lds + 32768 + r0 * 256), 16, 0, 0);
        }
        __syncthreads();

        f32x16 sacc[4] = {};
        __builtin_amdgcn_s_setprio(1);
#pragma unroll
        for (int vt = 0; vt < 4; ++vt) {
            const int row = vt * 32 + l31;
            const unsigned rb = row * 256;
            const unsigned sw = (row & 7) << 4;
#pragma unroll
            for (int ks = 0; ks < 8; ++ks) {
                bf16x8 a = *reinterpret_cast<const bf16x8*>(
                    lds + rb + ((ks * 32 + hi * 16) ^ sw));
                sacc[vt] = __builtin_amdgcn_mfma_f32_32x32x16_bf16(a, qfrag[ks], sacc[vt], 0, 0, 0);
            }
        }
        __builtin_amdgcn_s_setprio(0);

#pragma unroll
        for (int vt = 0; vt < 4; ++vt)
#pragma unroll
            for (int r = 0; r < 16; ++r) {
                float e = __expf(sacc[vt][r] * SCALE);
                sacc[vt][r] = e;
                sden_loc += e;
            }

        unsigned pw[8][4];
#pragma unroll
        for (int g = 0; g < 8; ++g) {
            const int vt = g >> 1, bs = (g & 1) * 8;
            unsigned pa = packbf2(sacc[vt][bs + 0], sacc[vt][bs + 1]);
            unsigned pc = packbf2(sacc[vt][bs + 2], sacc[vt][bs + 3]);
            unsigned pb = packbf2(sacc[vt][bs + 4], sacc[vt][bs + 5]);
            unsigned pd = packbf2(sacc[vt][bs + 6], sacc[vt][bs + 7]);
            unsigned sa = __shfl_xor(pa, 32);
            unsigned sb = __shfl_xor(pb, 32);
            unsigned sc = __shfl_xor(pc, 32);
            unsigned sd = __shfl_xor(pd, 32);
            pw[g][0] = hi ? sb : pa;
            pw[g][1] = hi ? sd : pc;
            pw[g][2] = hi ? pb : sa;
            pw[g][3] = hi ? pd : sc;
        }

        __builtin_amdgcn_s_setprio(1);
#pragma unroll
        for (int ct = 0; ct < 4; ++ct) {
            const int row = ct * 32 + l31;
            const unsigned rb = 32768 + row * 256;
            const unsigned sw = (row & 7) << 4;
#pragma unroll
            for (int g = 0; g < 8; ++g) {
                bf16x8 va = *reinterpret_cast<const bf16x8*>(
                    lds + rb + ((g * 32 + hi * 16) ^ sw));
                u32x4 pv = {pw[g][0], pw[g][1], pw[g][2], pw[g][3]};
                oacc[ct] = __builtin_amdgcn_mfma_f32_32x32x16_bf16(
                    va, __builtin_bit_cast(bf16x8, pv), oacc[ct], 0, 0, 0);
            }
        }
        __builtin_amdgcn_s_setprio(0);
        __syncthreads();
    }

    const float sden = sden_loc + __shfl_xor(sden_loc, 32);
    const float inv = 1.f / sden;
    const size_t base0 = (size_t)b * C * HW + (size_t)h * W + w0 + l31;
#pragma unroll
    for (int ct = 0; ct < 4; ++ct)
#pragma unroll
        for (int r = 0; r < 16; ++r) {
            const int c = ct * 32 + (r & 3) + 8 * (r >> 2) + 4 * hi;
            const size_t a = base0 + (size_t)c * HW;
            out[a] = x[a] + oacc[ct][r] * inv * coef[c];
        }
}

// ---------------------------------------------------------------------------
extern "C" void kernel_launch(void* const* d_in, const int* in_sizes, int n_in,
                              void* d_out, int out_size, void* d_ws, size_t ws_size,
                              hipStream_t stream) {
    (void)in_sizes; (void)n_in; (void)out_size; (void)ws_size;
    const float* x_l   = (const float*)d_in[0];
    const float* x_r   = (const float*)d_in[1];
    const float* Wl_m  = (const float*)d_in[2];
    const float* Wr_m  = (const float*)d_in[3];
    const float* dw_l  = (const float*)d_in[4];
    const float* dw_r  = (const float*)d_in[5];
    const float* lnl_w = (const float*)d_in[6];
    const float* lnl_b = (const float*)d_in[7];
    const float* lnr_w = (const float*)d_in[8];
    const float* lnr_b = (const float*)d_in[9];
    const float* Wq_l  = (const float*)d_in[10];
    const float* bq_l  = (const float*)d_in[11];
    const float* Wq_r  = (const float*)d_in[12];
    const float* bq_r  = (const float*)d_in[13];
    const float* beta  = (const float*)d_in[14];
    const float* gamma = (const float*)d_in[15];

    char* ws = (char*)d_ws;
    unsigned short* ymid_l   = (unsigned short*)(ws + 0);            // 50,331,648
    unsigned short* ymid_r   = (unsigned short*)(ws + 50331648);     // 50,331,648
    unsigned short* VT_l     = (unsigned short*)(ws + 150994944);    // 25,165,824
    unsigned short* VT_r     = (unsigned short*)(ws + 176160768);    // 25,165,824
    unsigned short* Q_l      = (unsigned short*)(ws + 201326592);    // 25,165,824
    unsigned short* Q_r      = (unsigned short*)(ws + 226492416);    // 25,165,824
    unsigned short* Wlb      = (unsigned short*)(ws + 251658240);    // 65,536
    unsigned short* Wrb      = (unsigned short*)(ws + 251723776);    // 65,536
    unsigned short* Wqlb     = (unsigned short*)(ws + 251789312);    // 32,768
    unsigned short* Wqrb     = (unsigned short*)(ws + 251822080);    // 32,768

    float* out_l = (float*)d_out;
    float* out_r = out_l + (size_t)B * C * HW;

    const dim3 blk(256);

    wcvt_kernel<<<24, blk, 0, stream>>>(Wl_m, Wr_m, Wq_l, Wq_r, Wlb, Wrb, Wqlb, Wqrb);

    conv1x1_mfma_kernel<<<3072, blk, 0, stream>>>(x_l, x_r, Wlb, Wrb, ymid_l, ymid_r);
    dwv_kernel<<<3072, dim3(128), 0, stream>>>(ymid_l, ymid_r, dw_l, dw_r, VT_l, VT_r);
    dwmid_kernel<<<3072, dim3(128), 0, stream>>>(ymid_l, ymid_r, dw_l, dw_r,
                                                 lnl_w, lnl_b, lnr_w, lnr_b,
                                                 Wqlb, Wqrb, bq_l, bq_r, Q_l, Q_r);
    fused_attn_kernel<<<1536, blk, 0, stream>>>(Q_l, Q_r, VT_l, VT_r,
                                                x_l, x_r, beta, gamma, out_l, out_r);
}

// Round 15
// 217.894 us; speedup vs baseline: 1.0553x; 1.0473x over previous
//
#include <hip/hip_runtime.h>
#include <hip/hip_bf16.h>

using bf16 = __hip_bfloat16;
typedef __attribute__((ext_vector_type(8))) short bf16x8;
typedef __attribute__((ext_vector_type(2))) float f32x2;
typedef __attribute__((ext_vector_type(4))) float f32x4;
typedef __attribute__((ext_vector_type(16))) float f32x16;
typedef __attribute__((ext_vector_type(4))) unsigned int u32x4;

#define DEVI __device__ __forceinline__

constexpr int B = 4, C = 128, C2 = 256, H = 96, W = 256;
constexpr int HW = H * W;            // 24576
constexpr int NPIX = B * HW;         // 98304
constexpr int BH = B * H;            // 384
constexpr float SCALE = 0.08838834764831845f; // 128^-0.5
constexpr float LN_EPS = 1e-5f;

DEVI float lo16(unsigned u) { return __builtin_bit_cast(float, u << 16); }
DEVI float hi16(unsigned u) { return __builtin_bit_cast(float, u & 0xffff0000u); }
DEVI unsigned short f2bu(float v) {
    bf16 b = __float2bfloat16(v);
    return __builtin_bit_cast(unsigned short, b);
}
DEVI unsigned packbf2(float a, float b) {
    return (unsigned)f2bu(a) | ((unsigned)f2bu(b) << 16);
}
DEVI f32x2 up2(unsigned p) { return f32x2{lo16(p), hi16(p)}; }

// ---------------------------------------------------------------------------
// W0: convert the 4 weight matrices fp32 -> bf16.
// ---------------------------------------------------------------------------
__global__ __launch_bounds__(256) void wcvt_kernel(
    const float* __restrict__ w0, const float* __restrict__ w1,
    const float* __restrict__ w2, const float* __restrict__ w3,
    unsigned short* __restrict__ o0, unsigned short* __restrict__ o1,
    unsigned short* __restrict__ o2, unsigned short* __restrict__ o3)
{
    const int id = blockIdx.x, t = threadIdx.x;
    const float* src; unsigned short* dst; int base;
    if (id < 8)       { src = w0; dst = o0; base = id * 4096; }
    else if (id < 16) { src = w1; dst = o1; base = (id - 8) * 4096; }
    else if (id < 20) { src = w2; dst = o2; base = (id - 16) * 4096; }
    else              { src = w3; dst = o3; base = (id - 20) * 4096; }
#pragma unroll
    for (int u = 0; u < 4; ++u) {
        int i = base + t * 16 + u * 4;
        float4 v = *reinterpret_cast<const float4*>(&src[i]);
        ushort4 o;
        o.x = f2bu(v.x); o.y = f2bu(v.y); o.z = f2bu(v.z); o.w = f2bu(v.w);
        *reinterpret_cast<ushort4*>(&dst[i]) = o;
    }
}

// ---------------------------------------------------------------------------
// K1: conv1x1 MFMA GEMM + fused NCHW->NHWC transpose, persistent 4-tile
// blocks with double-buffered LDS and T14 async staging:
//   LOADX(t+1) issued BEFORE COMPUTE(t) -> HBM/L3 latency hides under MFMA;
//   wfrag loaded once per block, reused 4x. One barrier per tile.
// Grid 768 (2 sides x 384 groups of 256 px).
// ---------------------------------------------------------------------------
__global__ __launch_bounds__(256) void conv1x1_mfma_kernel(
    const float* __restrict__ x_l, const float* __restrict__ x_r,
    const unsigned short* __restrict__ Wb_l, const unsigned short* __restrict__ Wb_r,
    unsigned short* __restrict__ y_l, unsigned short* __restrict__ y_r)
{
    __shared__ unsigned char xs[2][64 * 256];    // double buffer, XOR-swizzled
    const int side = blockIdx.x & 1;
    const int u = blockIdx.x >> 1;               // 0..383: 256-px groups
    const float* x = side ? x_r : x_l;
    const unsigned short* Wb = side ? Wb_r : Wb_l;
    unsigned short* y = side ? y_r : y_l;

    const int t = threadIdx.x;
    const int b = (u * 256) / HW;
    const int hw_base = (u * 256) % HW;

    const int lane = t & 63, wid = t >> 6;       // wid = oc quarter
    const int l15 = lane & 15, l4 = lane >> 4;
    const int px4 = (t & 15) * 4;                // staging: 4 px
    const int c8 = (t >> 4) * 8;                 // staging: 8 channels

    // ---- hoist all W B-frags for this wave's oc quarter ----
    bf16x8 wfrag[4][4];                          // [kk][nt]
#pragma unroll
    for (int kk = 0; kk < 4; ++kk)
#pragma unroll
        for (int nt = 0; nt < 4; ++nt)
            wfrag[kk][nt] = *reinterpret_cast<const bf16x8*>(
                &Wb[(size_t)(wid * 64 + nt * 16 + l15) * C + kk * 32 + l4 * 8]);

    float v_[8][4];                              // staged fp32 tile slice

    // LOADX: issue 8 global float4 loads for tile `tile`
#define LOADX(tile)                                                         \
    {                                                                       \
        _Pragma("unroll")                                                   \
        for (int j = 0; j < 8; ++j) {                                       \
            float4 v = *reinterpret_cast<const float4*>(                    \
                &x[((size_t)b * C + c8 + j) * HW + hw_base + (tile) * 64 + px4]); \
            v_[j][0] = v.x; v_[j][1] = v.y; v_[j][2] = v.z; v_[j][3] = v.w; \
        }                                                                   \
    }

    // WRITELDS: convert + write staged slice into buffer `bf`
#define WRITELDS(bf)                                                        \
    {                                                                       \
        _Pragma("unroll")                                                   \
        for (int i = 0; i < 4; ++i) {                                       \
            const int px = px4 + i;                                         \
            uint4 o;                                                        \
            o.x = packbf2(v_[0][i], v_[1][i]);                              \
            o.y = packbf2(v_[2][i], v_[3][i]);                              \
            o.z = packbf2(v_[4][i], v_[5][i]);                              \
            o.w = packbf2(v_[6][i], v_[7][i]);                              \
            const unsigned addr = (unsigned)(px * 256) +                    \
                (((unsigned)(c8 * 2)) ^ (unsigned)((px & 7) << 4));         \
            *reinterpret_cast<uint4*>(xs[bf] + addr) = o;                   \
        }                                                                   \
    }

    LOADX(0);
    WRITELDS(0);
    __syncthreads();

    for (int tile = 0; tile < 4; ++tile) {
        const int buf = tile & 1;
        if (tile < 3) LOADX(tile + 1);           // issue next-tile loads early

        f32x4 acc[4][4] = {};
#pragma unroll
        for (int kk = 0; kk < 4; ++kk) {
            const int k0b = (kk * 32 + l4 * 8) * 2;
            bf16x8 a[4];
#pragma unroll
            for (int mt = 0; mt < 4; ++mt) {
                const int pxl = mt * 16 + l15;
                const unsigned aaddr = (unsigned)(pxl * 256) +
                    (((unsigned)k0b) ^ (unsigned)((pxl & 7) << 4));
                a[mt] = *reinterpret_cast<const bf16x8*>(xs[buf] + aaddr);
            }
#pragma unroll
            for (int mt = 0; mt < 4; ++mt)
#pragma unroll
                for (int nt = 0; nt < 4; ++nt)
                    acc[mt][nt] = __builtin_amdgcn_mfma_f32_16x16x32_bf16(
                        wfrag[kk][nt], a[mt], acc[mt][nt], 0, 0, 0);
        }
        // store: D[oc][px], lane l15 = px, regs = 4 consecutive oc
#pragma unroll
        for (int mt = 0; mt < 4; ++mt) {
            const size_t px = (size_t)(b * HW + hw_base + tile * 64 + mt * 16 + l15);
#pragma unroll
            for (int nt = 0; nt < 4; ++nt) {
                const int oc = wid * 64 + nt * 16 + l4 * 4;
                uint2 o;
                o.x = packbf2(acc[mt][nt][0], acc[mt][nt][1]);
                o.y = packbf2(acc[mt][nt][2], acc[mt][nt][3]);
                *reinterpret_cast<uint2*>(&y[px * C2 + oc]) = o;
            }
        }

        if (tile < 3) {
            WRITELDS(buf ^ 1);                   // other buffer: safe pre-barrier
            __syncthreads();
        }
    }
#undef LOADX
#undef WRITELDS
}

// ---------------------------------------------------------------------------
// K2a: depthwise 3x3, V channels only (c<128) -> VT[bh][c][w], direct from
// registers. 128-thr blocks, zero LDS, zero barriers -> pure streaming.
// ---------------------------------------------------------------------------
__global__ __launch_bounds__(128) void dwv_kernel(
    const unsigned short* __restrict__ y_l, const unsigned short* __restrict__ y_r,
    const float* __restrict__ dwk_l, const float* __restrict__ dwk_r,
    unsigned short* __restrict__ VT_l, unsigned short* __restrict__ VT_r)
{
    const int side = blockIdx.x & 1;
    const int u = blockIdx.x >> 1;             // 0..1535
    const unsigned short* y = side ? y_r : y_l;
    const float* dwk = side ? dwk_r : dwk_l;
    unsigned short* VT = side ? VT_r : VT_l;

    const int t = threadIdx.x;
    const int wt = u & 3;
    const int bh = u >> 2;
    const int h = bh % H;
    const int ch8 = t & 15, wi = t >> 4;       // 16 c-octets x 8 w-groups
    const int c0 = ch8 * 8;
    const int wbase = wt * 64 + wi * 8;

    f32x2 acc2[8][4] = {};
#pragma unroll
    for (int dh = 0; dh < 3; ++dh) {
        const int hh = h + dh - 1;
        if ((unsigned)hh >= (unsigned)H) continue;
        f32x2 wt0[4], wt1[4], wt2[4];
#pragma unroll
        for (int k = 0; k < 4; ++k) {
            const float* d0 = dwk + (c0 + 2 * k) * 9 + dh * 3;
            const float* d1 = dwk + (c0 + 2 * k + 1) * 9 + dh * 3;
            wt0[k] = f32x2{d0[0], d1[0]};
            wt1[k] = f32x2{d0[1], d1[1]};
            wt2[k] = f32x2{d0[2], d1[2]};
        }
        const unsigned short* yrow = y + (size_t)(bh + dh - 1) * W * C2 + c0;
        uint4 uu[10];
#pragma unroll
        for (int j = 0; j < 10; ++j) {
            const int ww = wbase - 1 + j;
            uint4 v = {0u, 0u, 0u, 0u};
            if ((unsigned)ww < 256u)
                v = *reinterpret_cast<const uint4*>(&yrow[(size_t)ww * C2]);
            uu[j] = v;
        }
#pragma unroll
        for (int j = 0; j < 10; ++j) {
            const unsigned arr[4] = {uu[j].x, uu[j].y, uu[j].z, uu[j].w};
            f32x2 v[4];
#pragma unroll
            for (int k = 0; k < 4; ++k) v[k] = up2(arr[k]);
            if (j < 8) {
#pragma unroll
                for (int k = 0; k < 4; ++k) acc2[j][k] += v[k] * wt0[k];
            }
            if (j >= 1 && j <= 8) {
#pragma unroll
                for (int k = 0; k < 4; ++k) acc2[j - 1][k] += v[k] * wt1[k];
            }
            if (j >= 2) {
#pragma unroll
                for (int k = 0; k < 4; ++k) acc2[j - 2][k] += v[k] * wt2[k];
            }
        }
    }
#pragma unroll
    for (int k = 0; k < 8; ++k) {
        uint4 o;
        o.x = packbf2(acc2[0][k >> 1][k & 1], acc2[1][k >> 1][k & 1]);
        o.y = packbf2(acc2[2][k >> 1][k & 1], acc2[3][k >> 1][k & 1]);
        o.z = packbf2(acc2[4][k >> 1][k & 1], acc2[5][k >> 1][k & 1]);
        o.w = packbf2(acc2[6][k >> 1][k & 1], acc2[7][k >> 1][k & 1]);
        *reinterpret_cast<uint4*>(&VT[((size_t)bh * C + c0 + k) * W + wbase]) = o;
    }
}

// ---------------------------------------------------------------------------
// K2b: depthwise 3x3 mid channels + LayerNorm + Q-GEMM. 128-thr blocks
// (2 waves), msb LDS only (16KB). Q-GEMM swapped operands -> uint2 stores.
// ---------------------------------------------------------------------------
__global__ __launch_bounds__(128) void dwmid_kernel(
    const unsigned short* __restrict__ y_l, const unsigned short* __restrict__ y_r,
    const float* __restrict__ dwk_l, const float* __restrict__ dwk_r,
    const float* __restrict__ lnw_l, const float* __restrict__ lnb_l,
    const float* __restrict__ lnw_r, const float* __restrict__ lnb_r,
    const unsigned short* __restrict__ Wq_l, const unsigned short* __restrict__ Wq_r,
    const float* __restrict__ bq_l, const float* __restrict__ bq_r,
    unsigned short* __restrict__ q_l, unsigned short* __restrict__ q_r)
{
    __shared__ unsigned char msb[64 * 256];    // [px][c] swizzled bf16
    __shared__ float lnwb[256];

    const int side = blockIdx.x & 1;
    const int u = blockIdx.x >> 1;             // 0..1535
    const unsigned short* y = side ? y_r : y_l;
    const float* dwk = side ? dwk_r : dwk_l;
    const float* lnw = side ? lnw_r : lnw_l;
    const float* lnb = side ? lnb_r : lnb_l;
    const unsigned short* Wqb = side ? Wq_r : Wq_l;
    const float* bq = side ? bq_r : bq_l;
    unsigned short* q = side ? q_r : q_l;

    const int t = threadIdx.x;
    const int wt = u & 3;
    const int bh = u >> 2;
    const int h = bh % H;
    const int ch8 = t & 15, wi = t >> 4;
    const int c0m = ch8 * 8;
    const int wbase = wt * 64 + wi * 8;

    lnwb[t] = lnw[t];
    lnwb[t + 128] = lnb[t];

    f32x2 acc2[8][4] = {};
#pragma unroll
    for (int dh = 0; dh < 3; ++dh) {
        const int hh = h + dh - 1;
        if ((unsigned)hh >= (unsigned)H) continue;
        f32x2 wt0[4], wt1[4], wt2[4];
#pragma unroll
        for (int k = 0; k < 4; ++k) {
            const float* d0 = dwk + (128 + c0m + 2 * k) * 9 + dh * 3;
            const float* d1 = dwk + (128 + c0m + 2 * k + 1) * 9 + dh * 3;
            wt0[k] = f32x2{d0[0], d1[0]};
            wt1[k] = f32x2{d0[1], d1[1]};
            wt2[k] = f32x2{d0[2], d1[2]};
        }
        const unsigned short* yrow = y + (size_t)(bh + dh - 1) * W * C2 + 128 + c0m;
        uint4 uu[10];
#pragma unroll
        for (int j = 0; j < 10; ++j) {
            const int ww = wbase - 1 + j;
            uint4 v = {0u, 0u, 0u, 0u};
            if ((unsigned)ww < 256u)
                v = *reinterpret_cast<const uint4*>(&yrow[(size_t)ww * C2]);
            uu[j] = v;
        }
#pragma unroll
        for (int j = 0; j < 10; ++j) {
            const unsigned arr[4] = {uu[j].x, uu[j].y, uu[j].z, uu[j].w};
            f32x2 v[4];
#pragma unroll
            for (int k = 0; k < 4; ++k) v[k] = up2(arr[k]);
            if (j < 8) {
#pragma unroll
                for (int k = 0; k < 4; ++k) acc2[j][k] += v[k] * wt0[k];
            }
            if (j >= 1 && j <= 8) {
#pragma unroll
                for (int k = 0; k < 4; ++k) acc2[j - 1][k] += v[k] * wt1[k];
            }
            if (j >= 2) {
#pragma unroll
                for (int k = 0; k < 4; ++k) acc2[j - 2][k] += v[k] * wt2[k];
            }
        }
    }

#pragma unroll
    for (int i = 0; i < 8; ++i) {
        uint4 o;
        o.x = packbf2(acc2[i][0].x, acc2[i][0].y);
        o.y = packbf2(acc2[i][1].x, acc2[i][1].y);
        o.z = packbf2(acc2[i][2].x, acc2[i][2].y);
        o.w = packbf2(acc2[i][3].x, acc2[i][3].y);
        const int pxl = wi * 8 + i;
        const unsigned addr =
            (unsigned)(pxl * 256 + c0m * 2) ^ (unsigned)((pxl & 7) << 4);
        *reinterpret_cast<uint4*>(msb + addr) = o;
    }
    __syncthreads();

    {
        const int px = t >> 1, qq = t & 1;
        uint4 raw[8];
#pragma unroll
        for (int v = 0; v < 8; ++v) {
            const unsigned addr =
                (unsigned)(px * 256 + qq * 128 + v * 16) ^ (unsigned)((px & 7) << 4);
            raw[v] = *reinterpret_cast<const uint4*>(msb + addr);
        }
        float s1 = 0.f, s2 = 0.f;
#pragma unroll
        for (int v = 0; v < 8; ++v) {
            const unsigned arr[4] = {raw[v].x, raw[v].y, raw[v].z, raw[v].w};
#pragma unroll
            for (int k = 0; k < 4; ++k) {
                float v0 = lo16(arr[k]), v1 = hi16(arr[k]);
                s1 += v0 + v1; s2 += v0 * v0 + v1 * v1;
            }
        }
        s1 += __shfl_xor(s1, 1); s2 += __shfl_xor(s2, 1);
        const float mu = s1 * (1.f / C);
        const float rs = rsqrtf(s2 * (1.f / C) - mu * mu + LN_EPS);
#pragma unroll
        for (int v = 0; v < 8; ++v) {
            const unsigned arr[4] = {raw[v].x, raw[v].y, raw[v].z, raw[v].w};
            float nv[8];
#pragma unroll
            for (int k = 0; k < 4; ++k) {
                int c = qq * 64 + v * 8 + k * 2;
                nv[k * 2]     = (lo16(arr[k]) - mu) * rs * lnwb[c] + lnwb[128 + c];
                nv[k * 2 + 1] = (hi16(arr[k]) - mu) * rs * lnwb[c + 1] + lnwb[128 + c + 1];
            }
            uint4 wv;
            wv.x = packbf2(nv[0], nv[1]); wv.y = packbf2(nv[2], nv[3]);
            wv.z = packbf2(nv[4], nv[5]); wv.w = packbf2(nv[6], nv[7]);
            const unsigned addr =
                (unsigned)(px * 256 + qq * 128 + v * 16) ^ (unsigned)((px & 7) << 4);
            *reinterpret_cast<uint4*>(msb + addr) = wv;
        }
    }
    __syncthreads();

    {
        const int lane = t & 63, wid = t >> 6;
        const int l15 = lane & 15, l4 = lane >> 4;
        f32x4 acc[2][8] = {};
        for (int kk = 0; kk < 4; ++kk) {
            const int k0 = kk * 32 + l4 * 8;
            bf16x8 a[2];
#pragma unroll
            for (int pt = 0; pt < 2; ++pt) {
                const int pxl = (wid * 2 + pt) * 16 + l15;
                const unsigned aaddr =
                    (unsigned)(pxl * 256 + k0 * 2) ^ (unsigned)((pxl & 7) << 4);
                a[pt] = *reinterpret_cast<const bf16x8*>(msb + aaddr);
            }
#pragma unroll
            for (int nt = 0; nt < 8; ++nt) {
                bf16x8 bv = *reinterpret_cast<const bf16x8*>(
                    &Wqb[(size_t)(nt * 16 + l15) * C + k0]);
#pragma unroll
                for (int pt = 0; pt < 2; ++pt)
                    acc[pt][nt] = __builtin_amdgcn_mfma_f32_16x16x32_bf16(bv, a[pt], acc[pt][nt], 0, 0, 0);
            }
        }
        const size_t px0 = (size_t)bh * W + wt * 64;
#pragma unroll
        for (int pt = 0; pt < 2; ++pt) {
            const size_t px = px0 + (wid * 2 + pt) * 16 + l15;
#pragma unroll
            for (int nt = 0; nt < 8; ++nt) {
                const int oc = nt * 16 + l4 * 4;
                const float4 bias = *reinterpret_cast<const float4*>(&bq[oc]);
                uint2 o;
                o.x = packbf2(acc[pt][nt][0] + bias.x, acc[pt][nt][1] + bias.y);
                o.y = packbf2(acc[pt][nt][2] + bias.z, acc[pt][nt][3] + bias.w);
                *reinterpret_cast<uint2*>(&q[px * C + oc]) = o;
            }
        }
    }
}

// ---------------------------------------------------------------------------
// FUSED attention v5: swapped-operand QK^T (S^T = K·Q^T, 32x32x16 MFMA),
// in-register softmax + P->B-frag conversion, K & VT staged in LDS.
// ---------------------------------------------------------------------------
__global__ __launch_bounds__(256, 2) void fused_attn_kernel(
    const unsigned short* __restrict__ Q_l, const unsigned short* __restrict__ Q_r,
    const unsigned short* __restrict__ VT_l, const unsigned short* __restrict__ VT_r,
    const float* __restrict__ x_l, const float* __restrict__ x_r,
    const float* __restrict__ beta, const float* __restrict__ gamma,
    float* __restrict__ out_l, float* __restrict__ out_r)
{
    __shared__ __align__(16) unsigned char lds[65536];  // K chunk 32KB | VT chunk 32KB
    const int bid = blockIdx.x;
    const int xcd = bid & 7;
    const int local = bid >> 3;          // 0..191
    const int bh = xcd * 48 + (local >> 2);
    const int sub = local & 3;
    const int side = sub & 1, half = sub >> 1;

    const unsigned short* Q  = side ? Q_r : Q_l;
    const unsigned short* K  = side ? Q_l : Q_r;
    const unsigned short* VT = side ? VT_l : VT_r;
    const float* x    = side ? x_r : x_l;
    const float* coef = side ? gamma : beta;
    float* out        = side ? out_r : out_l;

    const int t = threadIdx.x;
    const int lane = t & 63, wv = t >> 6;
    const int l31 = lane & 31, hi = lane >> 5;
    const int b = bh / H, h = bh % H;
    const int w0 = half * 128 + wv * 32;     // this wave's 32 q-rows

    const unsigned short* qrow = Q + ((size_t)bh * W + w0 + l31) * C + hi * 8;
    bf16x8 qfrag[8];
#pragma unroll
    for (int ks = 0; ks < 8; ++ks)
        qfrag[ks] = *reinterpret_cast<const bf16x8*>(qrow + ks * 16);

    const char* kg = (const char*)(K + (size_t)bh * W * C);
    const char* vg = (const char*)(VT + (size_t)bh * C * W);
    const int srow = lane >> 4;
    const int scol = (lane & 15) * 16;

    float sden_loc = 0.f;
    f32x16 oacc[4] = {};

    for (int ci = 0; ci < 2; ++ci) {
#pragma unroll
        for (int i = 0; i < 8; ++i) {
            const int r0 = wv * 32 + i * 4;
            const int row = r0 + srow;
            const char* src = kg + (size_t)(ci * 128 + row) * 256 + (scol ^ ((row & 7) << 4));
            __builtin_amdgcn_global_load_lds(
                (const __attribute__((address_space(1))) void*)src,
                (__attribute__((address_space(3))) void*)(lds + r0 * 256), 16, 0, 0);
        }
#pragma unroll
        for (int i = 0; i < 8; ++i) {
            const int r0 = wv * 32 + i * 4;
            const int row = r0 + srow;
            const char* src = vg + (size_t)row * 512 + ci * 256 + (scol ^ ((row & 7) << 4));
            __builtin_amdgcn_global_load_lds(
                (const __attribute__((address_space(1))) void*)src,
                (__attribute__((address_space(3))) void*)(lds + 32768 + r0 * 256), 16, 0, 0);
        }
        __syncthreads();

        f32x16 sacc[4] = {};
        __builtin_amdgcn_s_setprio(1);
#pragma unroll
        for (int vt = 0; vt < 4; ++vt) {
            const int row = vt * 32 + l31;
            const unsigned rb = row * 256;
            const unsigned sw = (row & 7) << 4;
#pragma unroll
            for (int ks = 0; ks < 8; ++ks) {
                bf16x8 a = *reinterpret_cast<const bf16x8*>(
                    lds + rb + ((ks * 32 + hi * 16) ^ sw));
                sacc[vt] = __builtin_amdgcn_mfma_f32_32x32x16_bf16(a, qfrag[ks], sacc[vt], 0, 0, 0);
            }
        }
        __builtin_amdgcn_s_setprio(0);

#pragma unroll
        for (int vt = 0; vt < 4; ++vt)
#pragma unroll
            for (int r = 0; r < 16; ++r) {
                float e = __expf(sacc[vt][r] * SCALE);
                sacc[vt][r] = e;
                sden_loc += e;
            }

        unsigned pw[8][4];
#pragma unroll
        for (int g = 0; g < 8; ++g) {
            const int vt = g >> 1, bs = (g & 1) * 8;
            unsigned pa = packbf2(sacc[vt][bs + 0], sacc[vt][bs + 1]);
            unsigned pc = packbf2(sacc[vt][bs + 2], sacc[vt][bs + 3]);
            unsigned pb = packbf2(sacc[vt][bs + 4], sacc[vt][bs + 5]);
            unsigned pd = packbf2(sacc[vt][bs + 6], sacc[vt][bs + 7]);
            unsigned sa = __shfl_xor(pa, 32);
            unsigned sb = __shfl_xor(pb, 32);
            unsigned sc = __shfl_xor(pc, 32);
            unsigned sd = __shfl_xor(pd, 32);
            pw[g][0] = hi ? sb : pa;
            pw[g][1] = hi ? sd : pc;
            pw[g][2] = hi ? pb : sa;
            pw[g][3] = hi ? pd : sc;
        }

        __builtin_amdgcn_s_setprio(1);
#pragma unroll
        for (int ct = 0; ct < 4; ++ct) {
            const int row = ct * 32 + l31;
            const unsigned rb = 32768 + row * 256;
            const unsigned sw = (row & 7) << 4;
#pragma unroll
            for (int g = 0; g < 8; ++g) {
                bf16x8 va = *reinterpret_cast<const bf16x8*>(
                    lds + rb + ((g * 32 + hi * 16) ^ sw));
                u32x4 pv = {pw[g][0], pw[g][1], pw[g][2], pw[g][3]};
                oacc[ct] = __builtin_amdgcn_mfma_f32_32x32x16_bf16(
                    va, __builtin_bit_cast(bf16x8, pv), oacc[ct], 0, 0, 0);
            }
        }
        __builtin_amdgcn_s_setprio(0);
        __syncthreads();
    }

    const float sden = sden_loc + __shfl_xor(sden_loc, 32);
    const float inv = 1.f / sden;
    const size_t base0 = (size_t)b * C * HW + (size_t)h * W + w0 + l31;
#pragma unroll
    for (int ct = 0; ct < 4; ++ct)
#pragma unroll
        for (int r = 0; r < 16; ++r) {
            const int c = ct * 32 + (r & 3) + 8 * (r >> 2) + 4 * hi;
            const size_t a = base0 + (size_t)c * HW;
            out[a] = x[a] + oacc[ct][r] * inv * coef[c];
        }
}

// ---------------------------------------------------------------------------
extern "C" void kernel_launch(void* const* d_in, const int* in_sizes, int n_in,
                              void* d_out, int out_size, void* d_ws, size_t ws_size,
                              hipStream_t stream) {
    (void)in_sizes; (void)n_in; (void)out_size; (void)ws_size;
    const float* x_l   = (const float*)d_in[0];
    const float* x_r   = (const float*)d_in[1];
    const float* Wl_m  = (const float*)d_in[2];
    const float* Wr_m  = (const float*)d_in[3];
    const float* dw_l  = (const float*)d_in[4];
    const float* dw_r  = (const float*)d_in[5];
    const float* lnl_w = (const float*)d_in[6];
    const float* lnl_b = (const float*)d_in[7];
    const float* lnr_w = (const float*)d_in[8];
    const float* lnr_b = (const float*)d_in[9];
    const float* Wq_l  = (const float*)d_in[10];
    const float* bq_l  = (const float*)d_in[11];
    const float* Wq_r  = (const float*)d_in[12];
    const float* bq_r  = (const float*)d_in[13];
    const float* beta  = (const float*)d_in[14];
    const float* gamma = (const float*)d_in[15];

    char* ws = (char*)d_ws;
    unsigned short* ymid_l   = (unsigned short*)(ws + 0);            // 50,331,648
    unsigned short* ymid_r   = (unsigned short*)(ws + 50331648);     // 50,331,648
    unsigned short* VT_l     = (unsigned short*)(ws + 150994944);    // 25,165,824
    unsigned short* VT_r     = (unsigned short*)(ws + 176160768);    // 25,165,824
    unsigned short* Q_l      = (unsigned short*)(ws + 201326592);    // 25,165,824
    unsigned short* Q_r      = (unsigned short*)(ws + 226492416);    // 25,165,824
    unsigned short* Wlb      = (unsigned short*)(ws + 251658240);    // 65,536
    unsigned short* Wrb      = (unsigned short*)(ws + 251723776);    // 65,536
    unsigned short* Wqlb     = (unsigned short*)(ws + 251789312);    // 32,768
    unsigned short* Wqrb     = (unsigned short*)(ws + 251822080);    // 32,768

    float* out_l = (float*)d_out;
    float* out_r = out_l + (size_t)B * C * HW;

    const dim3 blk(256);

    wcvt_kernel<<<24, blk, 0, stream>>>(Wl_m, Wr_m, Wq_l, Wq_r, Wlb, Wrb, Wqlb, Wqrb);

    conv1x1_mfma_kernel<<<768, blk, 0, stream>>>(x_l, x_r, Wlb, Wrb, ymid_l, ymid_r);
    dwv_kernel<<<3072, dim3(128), 0, stream>>>(ymid_l, ymid_r, dw_l, dw_r, VT_l, VT_r);
    dwmid_kernel<<<3072, dim3(128), 0, stream>>>(ymid_l, ymid_r, dw_l, dw_r,
                                                 lnl_w, lnl_b, lnr_w, lnr_b,
                                                 Wqlb, Wqrb, bq_l, bq_r, Q_l, Q_r);
    fused_attn_kernel<<<1536, blk, 0, stream>>>(Q_l, Q_r, VT_l, VT_r,
                                                x_l, x_r, beta, gamma, out_l, out_r);
}

// Round 16
// 216.568 us; speedup vs baseline: 1.0618x; 1.0061x over previous
//
#include <hip/hip_runtime.h>
#include <hip/hip_bf16.h>

using bf16 = __hip_bfloat16;
typedef __attribute__((ext_vector_type(8))) short bf16x8;
typedef __attribute__((ext_vector_type(2))) float f32x2;
typedef __attribute__((ext_vector_type(4))) float f32x4;
typedef __attribute__((ext_vector_type(16))) float f32x16;
typedef __attribute__((ext_vector_type(4))) unsigned int u32x4;

#define DEVI __device__ __forceinline__

constexpr int B = 4, C = 128, C2 = 256, H = 96, W = 256;
constexpr int HW = H * W;            // 24576
constexpr int NPIX = B * HW;         // 98304
constexpr int BH = B * H;            // 384
constexpr float SCALE = 0.08838834764831845f; // 128^-0.5
constexpr float LN_EPS = 1e-5f;

DEVI float lo16(unsigned u) { return __builtin_bit_cast(float, u << 16); }
DEVI float hi16(unsigned u) { return __builtin_bit_cast(float, u & 0xffff0000u); }
DEVI unsigned short f2bu(float v) {
    bf16 b = __float2bfloat16(v);
    return __builtin_bit_cast(unsigned short, b);
}
DEVI unsigned packbf2(float a, float b) {
    return (unsigned)f2bu(a) | ((unsigned)f2bu(b) << 16);
}
DEVI f32x2 up2(unsigned p) { return f32x2{lo16(p), hi16(p)}; }

// ---------------------------------------------------------------------------
// W0: convert the 4 weight matrices fp32 -> bf16.
// ---------------------------------------------------------------------------
__global__ __launch_bounds__(256) void wcvt_kernel(
    const float* __restrict__ w0, const float* __restrict__ w1,
    const float* __restrict__ w2, const float* __restrict__ w3,
    unsigned short* __restrict__ o0, unsigned short* __restrict__ o1,
    unsigned short* __restrict__ o2, unsigned short* __restrict__ o3)
{
    const int id = blockIdx.x, t = threadIdx.x;
    const float* src; unsigned short* dst; int base;
    if (id < 8)       { src = w0; dst = o0; base = id * 4096; }
    else if (id < 16) { src = w1; dst = o1; base = (id - 8) * 4096; }
    else if (id < 20) { src = w2; dst = o2; base = (id - 16) * 4096; }
    else              { src = w3; dst = o3; base = (id - 20) * 4096; }
#pragma unroll
    for (int u = 0; u < 4; ++u) {
        int i = base + t * 16 + u * 4;
        float4 v = *reinterpret_cast<const float4*>(&src[i]);
        ushort4 o;
        o.x = f2bu(v.x); o.y = f2bu(v.y); o.z = f2bu(v.z); o.w = f2bu(v.w);
        *reinterpret_cast<ushort4*>(&dst[i]) = o;
    }
}

// ---------------------------------------------------------------------------
// K1: conv1x1 MFMA GEMM + fused NCHW->NHWC transpose, persistent 4-tile
// blocks with double-buffered LDS (round-15, kept verbatim).
// ---------------------------------------------------------------------------
__global__ __launch_bounds__(256) void conv1x1_mfma_kernel(
    const float* __restrict__ x_l, const float* __restrict__ x_r,
    const unsigned short* __restrict__ Wb_l, const unsigned short* __restrict__ Wb_r,
    unsigned short* __restrict__ y_l, unsigned short* __restrict__ y_r)
{
    __shared__ unsigned char xs[2][64 * 256];
    const int side = blockIdx.x & 1;
    const int u = blockIdx.x >> 1;               // 0..383: 256-px groups
    const float* x = side ? x_r : x_l;
    const unsigned short* Wb = side ? Wb_r : Wb_l;
    unsigned short* y = side ? y_r : y_l;

    const int t = threadIdx.x;
    const int b = (u * 256) / HW;
    const int hw_base = (u * 256) % HW;

    const int lane = t & 63, wid = t >> 6;
    const int l15 = lane & 15, l4 = lane >> 4;
    const int px4 = (t & 15) * 4;
    const int c8 = (t >> 4) * 8;

    bf16x8 wfrag[4][4];
#pragma unroll
    for (int kk = 0; kk < 4; ++kk)
#pragma unroll
        for (int nt = 0; nt < 4; ++nt)
            wfrag[kk][nt] = *reinterpret_cast<const bf16x8*>(
                &Wb[(size_t)(wid * 64 + nt * 16 + l15) * C + kk * 32 + l4 * 8]);

    float v_[8][4];

#define LOADX(tile)                                                         \
    {                                                                       \
        _Pragma("unroll")                                                   \
        for (int j = 0; j < 8; ++j) {                                       \
            float4 v = *reinterpret_cast<const float4*>(                    \
                &x[((size_t)b * C + c8 + j) * HW + hw_base + (tile) * 64 + px4]); \
            v_[j][0] = v.x; v_[j][1] = v.y; v_[j][2] = v.z; v_[j][3] = v.w; \
        }                                                                   \
    }

#define WRITELDS(bf)                                                        \
    {                                                                       \
        _Pragma("unroll")                                                   \
        for (int i = 0; i < 4; ++i) {                                       \
            const int px = px4 + i;                                         \
            uint4 o;                                                        \
            o.x = packbf2(v_[0][i], v_[1][i]);                              \
            o.y = packbf2(v_[2][i], v_[3][i]);                              \
            o.z = packbf2(v_[4][i], v_[5][i]);                              \
            o.w = packbf2(v_[6][i], v_[7][i]);                              \
            const unsigned addr = (unsigned)(px * 256) +                    \
                (((unsigned)(c8 * 2)) ^ (unsigned)((px & 7) << 4));         \
            *reinterpret_cast<uint4*>(xs[bf] + addr) = o;                   \
        }                                                                   \
    }

    LOADX(0);
    WRITELDS(0);
    __syncthreads();

    for (int tile = 0; tile < 4; ++tile) {
        const int buf = tile & 1;
        if (tile < 3) LOADX(tile + 1);

        f32x4 acc[4][4] = {};
#pragma unroll
        for (int kk = 0; kk < 4; ++kk) {
            const int k0b = (kk * 32 + l4 * 8) * 2;
            bf16x8 a[4];
#pragma unroll
            for (int mt = 0; mt < 4; ++mt) {
                const int pxl = mt * 16 + l15;
                const unsigned aaddr = (unsigned)(pxl * 256) +
                    (((unsigned)k0b) ^ (unsigned)((pxl & 7) << 4));
                a[mt] = *reinterpret_cast<const bf16x8*>(xs[buf] + aaddr);
            }
#pragma unroll
            for (int mt = 0; mt < 4; ++mt)
#pragma unroll
                for (int nt = 0; nt < 4; ++nt)
                    acc[mt][nt] = __builtin_amdgcn_mfma_f32_16x16x32_bf16(
                        wfrag[kk][nt], a[mt], acc[mt][nt], 0, 0, 0);
        }
#pragma unroll
        for (int mt = 0; mt < 4; ++mt) {
            const size_t px = (size_t)(b * HW + hw_base + tile * 64 + mt * 16 + l15);
#pragma unroll
            for (int nt = 0; nt < 4; ++nt) {
                const int oc = wid * 64 + nt * 16 + l4 * 4;
                uint2 o;
                o.x = packbf2(acc[mt][nt][0], acc[mt][nt][1]);
                o.y = packbf2(acc[mt][nt][2], acc[mt][nt][3]);
                *reinterpret_cast<uint2*>(&y[px * C2 + oc]) = o;
            }
        }

        if (tile < 3) {
            WRITELDS(buf ^ 1);
            __syncthreads();
        }
    }
#undef LOADX
#undef WRITELDS
}

// ---------------------------------------------------------------------------
// K2a: depthwise 3x3, V channels -> VT, register-direct (round-13, verbatim).
// ---------------------------------------------------------------------------
__global__ __launch_bounds__(128) void dwv_kernel(
    const unsigned short* __restrict__ y_l, const unsigned short* __restrict__ y_r,
    const float* __restrict__ dwk_l, const float* __restrict__ dwk_r,
    unsigned short* __restrict__ VT_l, unsigned short* __restrict__ VT_r)
{
    const int side = blockIdx.x & 1;
    const int u = blockIdx.x >> 1;
    const unsigned short* y = side ? y_r : y_l;
    const float* dwk = side ? dwk_r : dwk_l;
    unsigned short* VT = side ? VT_r : VT_l;

    const int t = threadIdx.x;
    const int wt = u & 3;
    const int bh = u >> 2;
    const int h = bh % H;
    const int ch8 = t & 15, wi = t >> 4;
    const int c0 = ch8 * 8;
    const int wbase = wt * 64 + wi * 8;

    f32x2 acc2[8][4] = {};
#pragma unroll
    for (int dh = 0; dh < 3; ++dh) {
        const int hh = h + dh - 1;
        if ((unsigned)hh >= (unsigned)H) continue;
        f32x2 wt0[4], wt1[4], wt2[4];
#pragma unroll
        for (int k = 0; k < 4; ++k) {
            const float* d0 = dwk + (c0 + 2 * k) * 9 + dh * 3;
            const float* d1 = dwk + (c0 + 2 * k + 1) * 9 + dh * 3;
            wt0[k] = f32x2{d0[0], d1[0]};
            wt1[k] = f32x2{d0[1], d1[1]};
            wt2[k] = f32x2{d0[2], d1[2]};
        }
        const unsigned short* yrow = y + (size_t)(bh + dh - 1) * W * C2 + c0;
        uint4 uu[10];
#pragma unroll
        for (int j = 0; j < 10; ++j) {
            const int ww = wbase - 1 + j;
            uint4 v = {0u, 0u, 0u, 0u};
            if ((unsigned)ww < 256u)
                v = *reinterpret_cast<const uint4*>(&yrow[(size_t)ww * C2]);
            uu[j] = v;
        }
#pragma unroll
        for (int j = 0; j < 10; ++j) {
            const unsigned arr[4] = {uu[j].x, uu[j].y, uu[j].z, uu[j].w};
            f32x2 v[4];
#pragma unroll
            for (int k = 0; k < 4; ++k) v[k] = up2(arr[k]);
            if (j < 8) {
#pragma unroll
                for (int k = 0; k < 4; ++k) acc2[j][k] += v[k] * wt0[k];
            }
            if (j >= 1 && j <= 8) {
#pragma unroll
                for (int k = 0; k < 4; ++k) acc2[j - 1][k] += v[k] * wt1[k];
            }
            if (j >= 2) {
#pragma unroll
                for (int k = 0; k < 4; ++k) acc2[j - 2][k] += v[k] * wt2[k];
            }
        }
    }
#pragma unroll
    for (int k = 0; k < 8; ++k) {
        uint4 o;
        o.x = packbf2(acc2[0][k >> 1][k & 1], acc2[1][k >> 1][k & 1]);
        o.y = packbf2(acc2[2][k >> 1][k & 1], acc2[3][k >> 1][k & 1]);
        o.z = packbf2(acc2[4][k >> 1][k & 1], acc2[5][k >> 1][k & 1]);
        o.w = packbf2(acc2[6][k >> 1][k & 1], acc2[7][k >> 1][k & 1]);
        *reinterpret_cast<uint4*>(&VT[((size_t)bh * C + c0 + k) * W + wbase]) = o;
    }
}

// ---------------------------------------------------------------------------
// K2b: depthwise 3x3 mid + LayerNorm + Q-GEMM (round-13, verbatim).
// ---------------------------------------------------------------------------
__global__ __launch_bounds__(128) void dwmid_kernel(
    const unsigned short* __restrict__ y_l, const unsigned short* __restrict__ y_r,
    const float* __restrict__ dwk_l, const float* __restrict__ dwk_r,
    const float* __restrict__ lnw_l, const float* __restrict__ lnb_l,
    const float* __restrict__ lnw_r, const float* __restrict__ lnb_r,
    const unsigned short* __restrict__ Wq_l, const unsigned short* __restrict__ Wq_r,
    const float* __restrict__ bq_l, const float* __restrict__ bq_r,
    unsigned short* __restrict__ q_l, unsigned short* __restrict__ q_r)
{
    __shared__ unsigned char msb[64 * 256];
    __shared__ float lnwb[256];

    const int side = blockIdx.x & 1;
    const int u = blockIdx.x >> 1;
    const unsigned short* y = side ? y_r : y_l;
    const float* dwk = side ? dwk_r : dwk_l;
    const float* lnw = side ? lnw_r : lnw_l;
    const float* lnb = side ? lnb_r : lnb_l;
    const unsigned short* Wqb = side ? Wq_r : Wq_l;
    const float* bq = side ? bq_r : bq_l;
    unsigned short* q = side ? q_r : q_l;

    const int t = threadIdx.x;
    const int wt = u & 3;
    const int bh = u >> 2;
    const int h = bh % H;
    const int ch8 = t & 15, wi = t >> 4;
    const int c0m = ch8 * 8;
    const int wbase = wt * 64 + wi * 8;

    lnwb[t] = lnw[t];
    lnwb[t + 128] = lnb[t];

    f32x2 acc2[8][4] = {};
#pragma unroll
    for (int dh = 0; dh < 3; ++dh) {
        const int hh = h + dh - 1;
        if ((unsigned)hh >= (unsigned)H) continue;
        f32x2 wt0[4], wt1[4], wt2[4];
#pragma unroll
        for (int k = 0; k < 4; ++k) {
            const float* d0 = dwk + (128 + c0m + 2 * k) * 9 + dh * 3;
            const float* d1 = dwk + (128 + c0m + 2 * k + 1) * 9 + dh * 3;
            wt0[k] = f32x2{d0[0], d1[0]};
            wt1[k] = f32x2{d0[1], d1[1]};
            wt2[k] = f32x2{d0[2], d1[2]};
        }
        const unsigned short* yrow = y + (size_t)(bh + dh - 1) * W * C2 + 128 + c0m;
        uint4 uu[10];
#pragma unroll
        for (int j = 0; j < 10; ++j) {
            const int ww = wbase - 1 + j;
            uint4 v = {0u, 0u, 0u, 0u};
            if ((unsigned)ww < 256u)
                v = *reinterpret_cast<const uint4*>(&yrow[(size_t)ww * C2]);
            uu[j] = v;
        }
#pragma unroll
        for (int j = 0; j < 10; ++j) {
            const unsigned arr[4] = {uu[j].x, uu[j].y, uu[j].z, uu[j].w};
            f32x2 v[4];
#pragma unroll
            for (int k = 0; k < 4; ++k) v[k] = up2(arr[k]);
            if (j < 8) {
#pragma unroll
                for (int k = 0; k < 4; ++k) acc2[j][k] += v[k] * wt0[k];
            }
            if (j >= 1 && j <= 8) {
#pragma unroll
                for (int k = 0; k < 4; ++k) acc2[j - 1][k] += v[k] * wt1[k];
            }
            if (j >= 2) {
#pragma unroll
                for (int k = 0; k < 4; ++k) acc2[j - 2][k] += v[k] * wt2[k];
            }
        }
    }

#pragma unroll
    for (int i = 0; i < 8; ++i) {
        uint4 o;
        o.x = packbf2(acc2[i][0].x, acc2[i][0].y);
        o.y = packbf2(acc2[i][1].x, acc2[i][1].y);
        o.z = packbf2(acc2[i][2].x, acc2[i][2].y);
        o.w = packbf2(acc2[i][3].x, acc2[i][3].y);
        const int pxl = wi * 8 + i;
        const unsigned addr =
            (unsigned)(pxl * 256 + c0m * 2) ^ (unsigned)((pxl & 7) << 4);
        *reinterpret_cast<uint4*>(msb + addr) = o;
    }
    __syncthreads();

    {
        const int px = t >> 1, qq = t & 1;
        uint4 raw[8];
#pragma unroll
        for (int v = 0; v < 8; ++v) {
            const unsigned addr =
                (unsigned)(px * 256 + qq * 128 + v * 16) ^ (unsigned)((px & 7) << 4);
            raw[v] = *reinterpret_cast<const uint4*>(msb + addr);
        }
        float s1 = 0.f, s2 = 0.f;
#pragma unroll
        for (int v = 0; v < 8; ++v) {
            const unsigned arr[4] = {raw[v].x, raw[v].y, raw[v].z, raw[v].w};
#pragma unroll
            for (int k = 0; k < 4; ++k) {
                float v0 = lo16(arr[k]), v1 = hi16(arr[k]);
                s1 += v0 + v1; s2 += v0 * v0 + v1 * v1;
            }
        }
        s1 += __shfl_xor(s1, 1); s2 += __shfl_xor(s2, 1);
        const float mu = s1 * (1.f / C);
        const float rs = rsqrtf(s2 * (1.f / C) - mu * mu + LN_EPS);
#pragma unroll
        for (int v = 0; v < 8; ++v) {
            const unsigned arr[4] = {raw[v].x, raw[v].y, raw[v].z, raw[v].w};
            float nv[8];
#pragma unroll
            for (int k = 0; k < 4; ++k) {
                int c = qq * 64 + v * 8 + k * 2;
                nv[k * 2]     = (lo16(arr[k]) - mu) * rs * lnwb[c] + lnwb[128 + c];
                nv[k * 2 + 1] = (hi16(arr[k]) - mu) * rs * lnwb[c + 1] + lnwb[128 + c + 1];
            }
            uint4 wv;
            wv.x = packbf2(nv[0], nv[1]); wv.y = packbf2(nv[2], nv[3]);
            wv.z = packbf2(nv[4], nv[5]); wv.w = packbf2(nv[6], nv[7]);
            const unsigned addr =
                (unsigned)(px * 256 + qq * 128 + v * 16) ^ (unsigned)((px & 7) << 4);
            *reinterpret_cast<uint4*>(msb + addr) = wv;
        }
    }
    __syncthreads();

    {
        const int lane = t & 63, wid = t >> 6;
        const int l15 = lane & 15, l4 = lane >> 4;
        f32x4 acc[2][8] = {};
        for (int kk = 0; kk < 4; ++kk) {
            const int k0 = kk * 32 + l4 * 8;
            bf16x8 a[2];
#pragma unroll
            for (int pt = 0; pt < 2; ++pt) {
                const int pxl = (wid * 2 + pt) * 16 + l15;
                const unsigned aaddr =
                    (unsigned)(pxl * 256 + k0 * 2) ^ (unsigned)((pxl & 7) << 4);
                a[pt] = *reinterpret_cast<const bf16x8*>(msb + aaddr);
            }
#pragma unroll
            for (int nt = 0; nt < 8; ++nt) {
                bf16x8 bv = *reinterpret_cast<const bf16x8*>(
                    &Wqb[(size_t)(nt * 16 + l15) * C + k0]);
#pragma unroll
                for (int pt = 0; pt < 2; ++pt)
                    acc[pt][nt] = __builtin_amdgcn_mfma_f32_16x16x32_bf16(bv, a[pt], acc[pt][nt], 0, 0, 0);
            }
        }
        const size_t px0 = (size_t)bh * W + wt * 64;
#pragma unroll
        for (int pt = 0; pt < 2; ++pt) {
            const size_t px = px0 + (wid * 2 + pt) * 16 + l15;
#pragma unroll
            for (int nt = 0; nt < 8; ++nt) {
                const int oc = nt * 16 + l4 * 4;
                const float4 bias = *reinterpret_cast<const float4*>(&bq[oc]);
                uint2 o;
                o.x = packbf2(acc[pt][nt][0] + bias.x, acc[pt][nt][1] + bias.y);
                o.y = packbf2(acc[pt][nt][2] + bias.z, acc[pt][nt][3] + bias.w);
                *reinterpret_cast<uint2*>(&q[px * C + oc]) = o;
            }
        }
    }
}

// ---------------------------------------------------------------------------
// FUSED attention v6: 4 chunks of 64 v-rows -> LDS 32KB -> 4 blocks/CU.
// Same swapped-operand QK^T / in-register softmax / P half-swap as v5.
// ---------------------------------------------------------------------------
__global__ __launch_bounds__(256) void fused_attn_kernel(
    const unsigned short* __restrict__ Q_l, const unsigned short* __restrict__ Q_r,
    const unsigned short* __restrict__ VT_l, const unsigned short* __restrict__ VT_r,
    const float* __restrict__ x_l, const float* __restrict__ x_r,
    const float* __restrict__ beta, const float* __restrict__ gamma,
    float* __restrict__ out_l, float* __restrict__ out_r)
{
    __shared__ __align__(16) unsigned char lds[32768];  // K 16KB | VT 16KB
    const int bid = blockIdx.x;
    const int xcd = bid & 7;
    const int local = bid >> 3;          // 0..191
    const int bh = xcd * 48 + (local >> 2);
    const int sub = local & 3;
    const int side = sub & 1, half = sub >> 1;

    const unsigned short* Q  = side ? Q_r : Q_l;
    const unsigned short* K  = side ? Q_l : Q_r;
    const unsigned short* VT = side ? VT_l : VT_r;
    const float* x    = side ? x_r : x_l;
    const float* coef = side ? gamma : beta;
    float* out        = side ? out_r : out_l;

    const int t = threadIdx.x;
    const int lane = t & 63, wv = t >> 6;
    const int l31 = lane & 31, hi = lane >> 5;
    const int b = bh / H, h = bh % H;
    const int w0 = half * 128 + wv * 32;     // this wave's 32 q-rows

    // ---- Q B-frags ----
    const unsigned short* qrow = Q + ((size_t)bh * W + w0 + l31) * C + hi * 8;
    bf16x8 qfrag[8];
#pragma unroll
    for (int ks = 0; ks < 8; ++ks)
        qfrag[ks] = *reinterpret_cast<const bf16x8*>(qrow + ks * 16);

    const char* kg = (const char*)(K + (size_t)bh * W * C);
    const char* vg = (const char*)(VT + (size_t)bh * C * W);

    float sden_loc = 0.f;
    f32x16 oacc[4] = {};

    for (int ci = 0; ci < 4; ++ci) {
        // ---- stage K chunk [64v][128c] (rows 256B) ----
        {
            const int rl = lane >> 4;            // 0..3
            const int cb = (lane & 15) * 16;
#pragma unroll
            for (int i = 0; i < 4; ++i) {
                const int row = (wv * 4 + i) * 4 + rl;     // 0..63
                const char* src = kg + (size_t)(ci * 64 + row) * 256
                                  + (cb ^ ((row & 7) << 4));
                __builtin_amdgcn_global_load_lds(
                    (const __attribute__((address_space(1))) void*)src,
                    (__attribute__((address_space(3))) void*)(lds + (wv * 4 + i) * 1024), 16, 0, 0);
            }
        }
        // ---- stage VT chunk [128c][64v] (rows 128B) ----
        {
            const int rl = lane >> 3;            // 0..7
            const int cb = (lane & 7) * 16;
#pragma unroll
            for (int i = 0; i < 4; ++i) {
                const int row = (wv * 4 + i) * 8 + rl;     // 0..127
                const char* src = vg + (size_t)row * 512 + ci * 128
                                  + (cb ^ ((row & 7) << 4));
                __builtin_amdgcn_global_load_lds(
                    (const __attribute__((address_space(1))) void*)src,
                    (__attribute__((address_space(3))) void*)(lds + 16384 + (wv * 4 + i) * 1024), 16, 0, 0);
            }
        }
        __syncthreads();

        // ---- S^T chunk = K_chunk · Q^T : 2 v-tiles of 32 ----
        f32x16 sacc[2] = {};
        __builtin_amdgcn_s_setprio(1);
#pragma unroll
        for (int vt = 0; vt < 2; ++vt) {
            const int row = vt * 32 + l31;
            const unsigned rb = row * 256;
            const unsigned sw = (row & 7) << 4;
#pragma unroll
            for (int ks = 0; ks < 8; ++ks) {
                bf16x8 a = *reinterpret_cast<const bf16x8*>(
                    lds + rb + ((ks * 32 + hi * 16) ^ sw));
                sacc[vt] = __builtin_amdgcn_mfma_f32_32x32x16_bf16(a, qfrag[ks], sacc[vt], 0, 0, 0);
            }
        }
        __builtin_amdgcn_s_setprio(0);

        // ---- softmax numerators + partial denominator ----
#pragma unroll
        for (int vt = 0; vt < 2; ++vt)
#pragma unroll
            for (int r = 0; r < 16; ++r) {
                float e = __expf(sacc[vt][r] * SCALE);
                sacc[vt][r] = e;
                sden_loc += e;
            }

        // ---- P -> bf16 B-frags (pack + half-swap); g = 0..3 per chunk ----
        unsigned pw[4][4];
#pragma unroll
        for (int g = 0; g < 4; ++g) {
            const int vt = g >> 1, bs = (g & 1) * 8;
            unsigned pa = packbf2(sacc[vt][bs + 0], sacc[vt][bs + 1]);
            unsigned pc = packbf2(sacc[vt][bs + 2], sacc[vt][bs + 3]);
            unsigned pb = packbf2(sacc[vt][bs + 4], sacc[vt][bs + 5]);
            unsigned pd = packbf2(sacc[vt][bs + 6], sacc[vt][bs + 7]);
            unsigned sa = __shfl_xor(pa, 32);
            unsigned sb = __shfl_xor(pb, 32);
            unsigned sc = __shfl_xor(pc, 32);
            unsigned sd = __shfl_xor(pd, 32);
            pw[g][0] = hi ? sb : pa;
            pw[g][1] = hi ? sd : pc;
            pw[g][2] = hi ? pb : sa;
            pw[g][3] = hi ? pd : sc;
        }

        // ---- O^T += VT_chunk · P^T : 4 c-tiles, 4 v-groups ----
        __builtin_amdgcn_s_setprio(1);
#pragma unroll
        for (int ct = 0; ct < 4; ++ct) {
            const int row = ct * 32 + l31;
            const unsigned rb = 16384 + row * 128;
            const unsigned sw = (row & 7) << 4;
#pragma unroll
            for (int g = 0; g < 4; ++g) {
                bf16x8 va = *reinterpret_cast<const bf16x8*>(
                    lds + rb + ((g * 32 + hi * 16) ^ sw));
                u32x4 pv = {pw[g][0], pw[g][1], pw[g][2], pw[g][3]};
                oacc[ct] = __builtin_amdgcn_mfma_f32_32x32x16_bf16(
                    va, __builtin_bit_cast(bf16x8, pv), oacc[ct], 0, 0, 0);
            }
        }
        __builtin_amdgcn_s_setprio(0);
        __syncthreads();
    }

    // ---- epilogue: lane holds O^T[c = ct*32+crow][w = w0+l31] ----
    const float sden = sden_loc + __shfl_xor(sden_loc, 32);
    const float inv = 1.f / sden;
    const size_t base0 = (size_t)b * C * HW + (size_t)h * W + w0 + l31;
#pragma unroll
    for (int ct = 0; ct < 4; ++ct)
#pragma unroll
        for (int r = 0; r < 16; ++r) {
            const int c = ct * 32 + (r & 3) + 8 * (r >> 2) + 4 * hi;
            const size_t a = base0 + (size_t)c * HW;
            out[a] = x[a] + oacc[ct][r] * inv * coef[c];
        }
}

// ---------------------------------------------------------------------------
extern "C" void kernel_launch(void* const* d_in, const int* in_sizes, int n_in,
                              void* d_out, int out_size, void* d_ws, size_t ws_size,
                              hipStream_t stream) {
    (void)in_sizes; (void)n_in; (void)out_size; (void)ws_size;
    const float* x_l   = (const float*)d_in[0];
    const float* x_r   = (const float*)d_in[1];
    const float* Wl_m  = (const float*)d_in[2];
    const float* Wr_m  = (const float*)d_in[3];
    const float* dw_l  = (const float*)d_in[4];
    const float* dw_r  = (const float*)d_in[5];
    const float* lnl_w = (const float*)d_in[6];
    const float* lnl_b = (const float*)d_in[7];
    const float* lnr_w = (const float*)d_in[8];
    const float* lnr_b = (const float*)d_in[9];
    const float* Wq_l  = (const float*)d_in[10];
    const float* bq_l  = (const float*)d_in[11];
    const float* Wq_r  = (const float*)d_in[12];
    const float* bq_r  = (const float*)d_in[13];
    const float* beta  = (const float*)d_in[14];
    const float* gamma = (const float*)d_in[15];

    char* ws = (char*)d_ws;
    unsigned short* ymid_l   = (unsigned short*)(ws + 0);            // 50,331,648
    unsigned short* ymid_r   = (unsigned short*)(ws + 50331648);     // 50,331,648
    unsigned short* VT_l     = (unsigned short*)(ws + 150994944);    // 25,165,824
    unsigned short* VT_r     = (unsigned short*)(ws + 176160768);    // 25,165,824
    unsigned short* Q_l      = (unsigned short*)(ws + 201326592);    // 25,165,824
    unsigned short* Q_r      = (unsigned short*)(ws + 226492416);    // 25,165,824
    unsigned short* Wlb      = (unsigned short*)(ws + 251658240);    // 65,536
    unsigned short* Wrb      = (unsigned short*)(ws + 251723776);    // 65,536
    unsigned short* Wqlb     = (unsigned short*)(ws + 251789312);    // 32,768
    unsigned short* Wqrb     = (unsigned short*)(ws + 251822080);    // 32,768

    float* out_l = (float*)d_out;
    float* out_r = out_l + (size_t)B * C * HW;

    const dim3 blk(256);

    wcvt_kernel<<<24, blk, 0, stream>>>(Wl_m, Wr_m, Wq_l, Wq_r, Wlb, Wrb, Wqlb, Wqrb);

    conv1x1_mfma_kernel<<<768, blk, 0, stream>>>(x_l, x_r, Wlb, Wrb, ymid_l, ymid_r);
    dwv_kernel<<<3072, dim3(128), 0, stream>>>(ymid_l, ymid_r, dw_l, dw_r, VT_l, VT_r);
    dwmid_kernel<<<3072, dim3(128), 0, stream>>>(ymid_l, ymid_r, dw_l, dw_r,
                                                 lnl_w, lnl_b, lnr_w, lnr_b,
                                                 Wqlb, Wqrb, bq_l, bq_r, Q_l, Q_r);
    fused_attn_kernel<<<1536, blk, 0, stream>>>(Q_l, Q_r, VT_l, VT_r,
                                                x_l, x_r, beta, gamma, out_l, out_r);
}